// Round 1
// baseline (1307.555 us; speedup 1.0000x reference)
//
#include <hip/hip_runtime.h>
#include <cstddef>

#define NEG_INF (-3.0e38f)

// ---------------------------------------------------------------------------
// SGEMM 128x128x16 tile, 256 threads, 8x8 microtile arranged as 2x2 of 4x4
// C[m][n] = sum_k A[m][k] * W[n][k]  (+bias, custom epilogue)
// ---------------------------------------------------------------------------

// QKV projection: A = x (8192x768), W = qkv_w (2304x768), bias qkv_b (2304)
// Epilogue scatters into q/k/v buffers laid out [96][1024][64], q scaled 0.125
__global__ __launch_bounds__(256) void qkv_gemm(
    const float* __restrict__ A, const float* __restrict__ W,
    const float* __restrict__ bias,
    float* __restrict__ qb, float* __restrict__ kb, float* __restrict__ vb)
{
    __shared__ float As[16][132];
    __shared__ float Bs[16][132];
    const int t  = threadIdx.x;
    const int tx = t & 15;        // column group
    const int ty = t >> 4;        // row group
    const int bc = blockIdx.x;    // over N = 2304 (18 blocks)
    const int br = blockIdx.y;    // over M = 8192 (64 blocks)

    const int lrow = t >> 2;            // 0..63
    const int lkq  = (t & 3) << 2;      // 0,4,8,12

    const float* Ap = A + (size_t)(br * 128 + lrow) * 768 + lkq;
    const float* Wp = W + (size_t)(bc * 128 + lrow) * 768 + lkq;

    float acc[2][2][4][4];
#pragma unroll
    for (int i = 0; i < 2; ++i)
#pragma unroll
        for (int j = 0; j < 2; ++j)
#pragma unroll
            for (int r = 0; r < 4; ++r)
#pragma unroll
                for (int w = 0; w < 4; ++w) acc[i][j][r][w] = 0.f;

    for (int k0 = 0; k0 < 768; k0 += 16) {
        float4 a0 = *(const float4*)(Ap + k0);
        float4 a1 = *(const float4*)(Ap + (size_t)64 * 768 + k0);
        float4 b0 = *(const float4*)(Wp + k0);
        float4 b1 = *(const float4*)(Wp + (size_t)64 * 768 + k0);
        __syncthreads();
        As[lkq + 0][lrow] = a0.x; As[lkq + 1][lrow] = a0.y;
        As[lkq + 2][lrow] = a0.z; As[lkq + 3][lrow] = a0.w;
        As[lkq + 0][lrow + 64] = a1.x; As[lkq + 1][lrow + 64] = a1.y;
        As[lkq + 2][lrow + 64] = a1.z; As[lkq + 3][lrow + 64] = a1.w;
        Bs[lkq + 0][lrow] = b0.x; Bs[lkq + 1][lrow] = b0.y;
        Bs[lkq + 2][lrow] = b0.z; Bs[lkq + 3][lrow] = b0.w;
        Bs[lkq + 0][lrow + 64] = b1.x; Bs[lkq + 1][lrow + 64] = b1.y;
        Bs[lkq + 2][lrow + 64] = b1.z; Bs[lkq + 3][lrow + 64] = b1.w;
        __syncthreads();
#pragma unroll
        for (int kk = 0; kk < 16; ++kk) {
            float4 av0 = *(const float4*)&As[kk][ty << 2];
            float4 av1 = *(const float4*)&As[kk][(ty << 2) + 64];
            float4 bv0 = *(const float4*)&Bs[kk][tx << 2];
            float4 bv1 = *(const float4*)&Bs[kk][(tx << 2) + 64];
            float av[2][4] = {{av0.x, av0.y, av0.z, av0.w}, {av1.x, av1.y, av1.z, av1.w}};
            float bv[2][4] = {{bv0.x, bv0.y, bv0.z, bv0.w}, {bv1.x, bv1.y, bv1.z, bv1.w}};
#pragma unroll
            for (int ii = 0; ii < 2; ++ii)
#pragma unroll
                for (int r = 0; r < 4; ++r)
#pragma unroll
                    for (int jj = 0; jj < 2; ++jj)
#pragma unroll
                        for (int w = 0; w < 4; ++w)
                            acc[ii][jj][r][w] += av[ii][r] * bv[jj][w];
        }
    }

    const int m0 = br * 128 + (ty << 2);
    const int n0 = bc * 128 + (tx << 2);
#pragma unroll
    for (int ii = 0; ii < 2; ++ii) {
#pragma unroll
        for (int r = 0; r < 4; ++r) {
            int m   = m0 + ii * 64 + r;
            int bb  = m >> 10;
            int tok = m & 1023;
#pragma unroll
            for (int jj = 0; jj < 2; ++jj) {
                int n     = n0 + jj * 64;
                int which = n / 768;            // 0=q 1=k 2=v (uniform over 4 cols)
                int c     = n - which * 768;
                int head  = c >> 6;
                int d     = c & 63;
                float sc  = (which == 0) ? 0.125f : 1.0f;   // hd^-0.5 = 1/8
                float4 val;
                val.x = (acc[ii][jj][r][0] + bias[n + 0]) * sc;
                val.y = (acc[ii][jj][r][1] + bias[n + 1]) * sc;
                val.z = (acc[ii][jj][r][2] + bias[n + 2]) * sc;
                val.w = (acc[ii][jj][r][3] + bias[n + 3]) * sc;
                float* dst = (which == 0) ? qb : ((which == 1) ? kb : vb);
                *(float4*)&dst[(((size_t)(bb * 12 + head) << 10) + tok) * 64 + d] = val;
            }
        }
    }
}

// Output projection: A = attn_out (8192x768), W = proj_w (768x768), plain epilogue
__global__ __launch_bounds__(256) void proj_gemm(
    const float* __restrict__ A, const float* __restrict__ W,
    const float* __restrict__ bias, float* __restrict__ Out)
{
    __shared__ float As[16][132];
    __shared__ float Bs[16][132];
    const int t  = threadIdx.x;
    const int tx = t & 15;
    const int ty = t >> 4;
    const int bc = blockIdx.x;    // over N = 768 (6 blocks)
    const int br = blockIdx.y;    // over M = 8192 (64 blocks)

    const int lrow = t >> 2;
    const int lkq  = (t & 3) << 2;

    const float* Ap = A + (size_t)(br * 128 + lrow) * 768 + lkq;
    const float* Wp = W + (size_t)(bc * 128 + lrow) * 768 + lkq;

    float acc[2][2][4][4];
#pragma unroll
    for (int i = 0; i < 2; ++i)
#pragma unroll
        for (int j = 0; j < 2; ++j)
#pragma unroll
            for (int r = 0; r < 4; ++r)
#pragma unroll
                for (int w = 0; w < 4; ++w) acc[i][j][r][w] = 0.f;

    for (int k0 = 0; k0 < 768; k0 += 16) {
        float4 a0 = *(const float4*)(Ap + k0);
        float4 a1 = *(const float4*)(Ap + (size_t)64 * 768 + k0);
        float4 b0 = *(const float4*)(Wp + k0);
        float4 b1 = *(const float4*)(Wp + (size_t)64 * 768 + k0);
        __syncthreads();
        As[lkq + 0][lrow] = a0.x; As[lkq + 1][lrow] = a0.y;
        As[lkq + 2][lrow] = a0.z; As[lkq + 3][lrow] = a0.w;
        As[lkq + 0][lrow + 64] = a1.x; As[lkq + 1][lrow + 64] = a1.y;
        As[lkq + 2][lrow + 64] = a1.z; As[lkq + 3][lrow + 64] = a1.w;
        Bs[lkq + 0][lrow] = b0.x; Bs[lkq + 1][lrow] = b0.y;
        Bs[lkq + 2][lrow] = b0.z; Bs[lkq + 3][lrow] = b0.w;
        Bs[lkq + 0][lrow + 64] = b1.x; Bs[lkq + 1][lrow + 64] = b1.y;
        Bs[lkq + 2][lrow + 64] = b1.z; Bs[lkq + 3][lrow + 64] = b1.w;
        __syncthreads();
#pragma unroll
        for (int kk = 0; kk < 16; ++kk) {
            float4 av0 = *(const float4*)&As[kk][ty << 2];
            float4 av1 = *(const float4*)&As[kk][(ty << 2) + 64];
            float4 bv0 = *(const float4*)&Bs[kk][tx << 2];
            float4 bv1 = *(const float4*)&Bs[kk][(tx << 2) + 64];
            float av[2][4] = {{av0.x, av0.y, av0.z, av0.w}, {av1.x, av1.y, av1.z, av1.w}};
            float bv[2][4] = {{bv0.x, bv0.y, bv0.z, bv0.w}, {bv1.x, bv1.y, bv1.z, bv1.w}};
#pragma unroll
            for (int ii = 0; ii < 2; ++ii)
#pragma unroll
                for (int r = 0; r < 4; ++r)
#pragma unroll
                    for (int jj = 0; jj < 2; ++jj)
#pragma unroll
                        for (int w = 0; w < 4; ++w)
                            acc[ii][jj][r][w] += av[ii][r] * bv[jj][w];
        }
    }

    const int m0 = br * 128 + (ty << 2);
    const int n0 = bc * 128 + (tx << 2);
#pragma unroll
    for (int ii = 0; ii < 2; ++ii) {
#pragma unroll
        for (int r = 0; r < 4; ++r) {
            int m = m0 + ii * 64 + r;
#pragma unroll
            for (int jj = 0; jj < 2; ++jj) {
                int n = n0 + jj * 64;
                float4 val;
                val.x = acc[ii][jj][r][0] + bias[n + 0];
                val.y = acc[ii][jj][r][1] + bias[n + 1];
                val.z = acc[ii][jj][r][2] + bias[n + 2];
                val.w = acc[ii][jj][r][3] + bias[n + 3];
                *(float4*)&Out[(size_t)m * 768 + n] = val;
            }
        }
    }
}

// ---------------------------------------------------------------------------
// Flash attention with decomposed rel-pos bias.
// Block = (bh, 32-query tile) = one full image row i of queries.
//   dist_h index = i - key_row + 31  (depends only on key row kb = key>>5)
//   dist_w index = j - key_col + 31  (j == local q index; key col = key&31)
// -> bias(q, key) = qh_tab[q][key>>5] + qw_tab[q][key&31], tables built once.
// ---------------------------------------------------------------------------
__global__ __launch_bounds__(256) void attn_kernel(
    const float* __restrict__ Q, const float* __restrict__ K,
    const float* __restrict__ V, const float* __restrict__ Rh,
    const float* __restrict__ Rw, float* __restrict__ Out)
{
    const int t  = threadIdx.x;
    const int qt = blockIdx.x;    // 0..31  (== image row i of this q tile)
    const int bh = blockIdx.y;    // 0..95
    const int b  = bh / 12;
    const int h  = bh - b * 12;
    const int q0 = qt << 5;

    __shared__ float Qs[32][68];
    __shared__ float Ks[64][68];
    __shared__ float Vs[64][68];
    __shared__ float Ss[32][68];
    __shared__ float qh_tab[32][33];
    __shared__ float qw_tab[32][33];
    __shared__ float m_s[32], l_s[32], alpha_s[32];
    __shared__ float red[256];

    const float* Qp = Q + ((size_t)bh * 1024 + q0) * 64;
    const float* Kp = K + (size_t)bh * 1024 * 64;
    const float* Vp = V + (size_t)bh * 1024 * 64;

    // Q tile 32x64
    for (int id = t; id < 512; id += 256) {
        int row = id >> 4, fo = (id & 15) << 2;
        *(float4*)&Qs[row][fo] = *(const float4*)(Qp + row * 64 + fo);
    }
    if (t < 32) { m_s[t] = NEG_INF; l_s[t] = 0.f; }
    __syncthreads();

    // bias tables: qh_tab[q][kb] = Q[q]·rel_h[qt-kb+31], qw_tab[q][l] = Q[q]·rel_w[q-l+31]
    for (int p = t; p < 1024; p += 256) {
        int qq = p >> 5, c = p & 31;
        const float* rh = Rh + (qt - c + 31) * 64;
        const float* rw = Rw + (qq - c + 31) * 64;
        float ah = 0.f, aw = 0.f;
        for (int c4 = 0; c4 < 64; c4 += 4) {
            float4 qv = *(const float4*)&Qs[qq][c4];
            float4 hv = *(const float4*)(rh + c4);
            float4 wv = *(const float4*)(rw + c4);
            ah += qv.x * hv.x + qv.y * hv.y + qv.z * hv.z + qv.w * hv.w;
            aw += qv.x * wv.x + qv.y * wv.y + qv.z * wv.z + qv.w * wv.w;
        }
        qh_tab[qq][c] = ah;
        qw_tab[qq][c] = aw;
    }
    __syncthreads();

    float o[8] = {0.f, 0.f, 0.f, 0.f, 0.f, 0.f, 0.f, 0.f};
    const int qr  = t >> 3;            // q row for S-pass / PV-pass
    const int kc0 = t & 7;             // key-column base (stride 8)
    const int d0  = (t & 7) << 3;      // head-dim slice for PV
    const int sq  = t & 31, sl = t >> 5;  // stats assignment

    for (int kt = 0; kt < 16; ++kt) {
        const int k0 = kt << 6;
        // K,V tiles 64x64
        for (int id = t; id < 1024; id += 256) {
            int row = id >> 4, fo = (id & 15) << 2;
            *(float4*)&Ks[row][fo] = *(const float4*)(Kp + (k0 + row) * 64 + fo);
            *(float4*)&Vs[row][fo] = *(const float4*)(Vp + (k0 + row) * 64 + fo);
        }
        __syncthreads();

        // S = Q·K^T + bias  (each thread: 1 q row x 8 key cols, stride 8)
        {
            float sacc[8];
#pragma unroll
            for (int jj = 0; jj < 8; ++jj) sacc[jj] = 0.f;
            for (int c4 = 0; c4 < 64; c4 += 4) {
                float4 qv = *(const float4*)&Qs[qr][c4];
#pragma unroll
                for (int jj = 0; jj < 8; ++jj) {
                    float4 kv = *(const float4*)&Ks[kc0 + (jj << 3)][c4];
                    sacc[jj] += qv.x * kv.x + qv.y * kv.y + qv.z * kv.z + qv.w * kv.w;
                }
            }
#pragma unroll
            for (int jj = 0; jj < 8; ++jj) {
                int kc = kc0 + (jj << 3);
                int kb = (k0 + kc) >> 5;
                Ss[qr][kc] = sacc[jj] + qh_tab[qr][kb] + qw_tab[qr][kc & 31];
            }
        }
        __syncthreads();

        // row max (8 slices per row)
        {
            float lm = NEG_INF;
#pragma unroll
            for (int ii = 0; ii < 8; ++ii) lm = fmaxf(lm, Ss[sq][(sl << 3) + ii]);
            red[(sl << 5) + sq] = lm;
        }
        __syncthreads();
        if (t < 32) {
            float m  = m_s[t];
            float mt = red[t];
#pragma unroll
            for (int s2 = 1; s2 < 8; ++s2) mt = fmaxf(mt, red[(s2 << 5) + t]);
            float mn   = fmaxf(m, mt);
            alpha_s[t] = __expf(m - mn);
            m_s[t]     = mn;
        }
        __syncthreads();

        // exp + row sum
        {
            float ps   = 0.f;
            float mrow = m_s[sq];
#pragma unroll
            for (int ii = 0; ii < 8; ++ii) {
                int idx = (sl << 3) + ii;
                float pe = __expf(Ss[sq][idx] - mrow);
                Ss[sq][idx] = pe;
                ps += pe;
            }
            red[(sl << 5) + sq] = ps;
        }
        __syncthreads();
        if (t < 32) {
            float s2sum = 0.f;
#pragma unroll
            for (int s2 = 0; s2 < 8; ++s2) s2sum += red[(s2 << 5) + t];
            l_s[t] = l_s[t] * alpha_s[t] + s2sum;
        }

        // O = O*alpha + P·V  (each thread: 1 q row x 8 head dims)
        {
            float al = alpha_s[qr];
#pragma unroll
            for (int j = 0; j < 8; ++j) o[j] *= al;
            for (int kk = 0; kk < 64; ++kk) {
                float pv  = Ss[qr][kk];
                float4 v0 = *(const float4*)&Vs[kk][d0];
                float4 v1 = *(const float4*)&Vs[kk][d0 + 4];
                o[0] += pv * v0.x; o[1] += pv * v0.y; o[2] += pv * v0.z; o[3] += pv * v0.w;
                o[4] += pv * v1.x; o[5] += pv * v1.y; o[6] += pv * v1.z; o[7] += pv * v1.w;
            }
        }
        __syncthreads();
    }

    const float inv = 1.0f / l_s[qr];
    float4 r0 = make_float4(o[0] * inv, o[1] * inv, o[2] * inv, o[3] * inv);
    float4 r1 = make_float4(o[4] * inv, o[5] * inv, o[6] * inv, o[7] * inv);
    float* dst = Out + ((size_t)(b * 1024 + q0 + qr)) * 768 + h * 64 + d0;
    *(float4*)dst       = r0;
    *(float4*)(dst + 4) = r1;
}

extern "C" void kernel_launch(void* const* d_in, const int* in_sizes, int n_in,
                              void* d_out, int out_size, void* d_ws, size_t ws_size,
                              hipStream_t stream) {
    const float* x      = (const float*)d_in[0];
    const float* qkv_w  = (const float*)d_in[1];
    const float* qkv_b  = (const float*)d_in[2];
    const float* proj_w = (const float*)d_in[3];
    const float* proj_b = (const float*)d_in[4];
    const float* rel_h  = (const float*)d_in[5];
    const float* rel_w  = (const float*)d_in[6];
    float* out = (float*)d_out;

    float* qbuf = (float*)d_ws;              // [96][1024][64]
    float* kbuf = qbuf + 6291456;
    float* vbuf = kbuf + 6291456;
    float* abuf = vbuf + 6291456;            // attn output (8192x768), pre-proj

    qkv_gemm<<<dim3(18, 64), 256, 0, stream>>>(x, qkv_w, qkv_b, qbuf, kbuf, vbuf);
    attn_kernel<<<dim3(32, 96), 256, 0, stream>>>(qbuf, kbuf, vbuf, rel_h, rel_w, abuf);
    proj_gemm<<<dim3(6, 64), 256, 0, stream>>>(abuf, proj_w, proj_b, out);
}

// Round 2
// 1035.197 us; speedup vs baseline: 1.2631x; 1.2631x over previous
//
#include <hip/hip_runtime.h>
#include <cstddef>

#define NEG_INF (-3.0e38f)

__device__ __forceinline__ unsigned short f2bf(float f) {
    union { float f; unsigned u; } v; v.f = f;
    unsigned r = v.u + 0x7fff + ((v.u >> 16) & 1);
    return (unsigned short)(r >> 16);
}

// ---------------------------------------------------------------------------
// SGEMM 128x128x16 tile, 256 threads, 8x8 microtile arranged as 2x2 of 4x4
// ---------------------------------------------------------------------------

// QKV projection. q -> fp32 [96][1024][64] (pre-scaled 0.125); k,v -> bf16.
__global__ __launch_bounds__(256) void qkv_gemm(
    const float* __restrict__ A, const float* __restrict__ W,
    const float* __restrict__ bias,
    float* __restrict__ qb, unsigned short* __restrict__ kb,
    unsigned short* __restrict__ vb)
{
    __shared__ float As[16][132];
    __shared__ float Bs[16][132];
    const int t  = threadIdx.x;
    const int tx = t & 15;
    const int ty = t >> 4;
    const int bc = blockIdx.x;    // N = 2304 (18 blocks)
    const int br = blockIdx.y;    // M = 8192 (64 blocks)

    const int lrow = t >> 2;
    const int lkq  = (t & 3) << 2;

    const float* Ap = A + (size_t)(br * 128 + lrow) * 768 + lkq;
    const float* Wp = W + (size_t)(bc * 128 + lrow) * 768 + lkq;

    float acc[2][2][4][4];
#pragma unroll
    for (int i = 0; i < 2; ++i)
#pragma unroll
        for (int j = 0; j < 2; ++j)
#pragma unroll
            for (int r = 0; r < 4; ++r)
#pragma unroll
                for (int w = 0; w < 4; ++w) acc[i][j][r][w] = 0.f;

    for (int k0 = 0; k0 < 768; k0 += 16) {
        float4 a0 = *(const float4*)(Ap + k0);
        float4 a1 = *(const float4*)(Ap + (size_t)64 * 768 + k0);
        float4 b0 = *(const float4*)(Wp + k0);
        float4 b1 = *(const float4*)(Wp + (size_t)64 * 768 + k0);
        __syncthreads();
        As[lkq + 0][lrow] = a0.x; As[lkq + 1][lrow] = a0.y;
        As[lkq + 2][lrow] = a0.z; As[lkq + 3][lrow] = a0.w;
        As[lkq + 0][lrow + 64] = a1.x; As[lkq + 1][lrow + 64] = a1.y;
        As[lkq + 2][lrow + 64] = a1.z; As[lkq + 3][lrow + 64] = a1.w;
        Bs[lkq + 0][lrow] = b0.x; Bs[lkq + 1][lrow] = b0.y;
        Bs[lkq + 2][lrow] = b0.z; Bs[lkq + 3][lrow] = b0.w;
        Bs[lkq + 0][lrow + 64] = b1.x; Bs[lkq + 1][lrow + 64] = b1.y;
        Bs[lkq + 2][lrow + 64] = b1.z; Bs[lkq + 3][lrow + 64] = b1.w;
        __syncthreads();
#pragma unroll
        for (int kk = 0; kk < 16; ++kk) {
            float4 av0 = *(const float4*)&As[kk][ty << 2];
            float4 av1 = *(const float4*)&As[kk][(ty << 2) + 64];
            float4 bv0 = *(const float4*)&Bs[kk][tx << 2];
            float4 bv1 = *(const float4*)&Bs[kk][(tx << 2) + 64];
            float av[2][4] = {{av0.x, av0.y, av0.z, av0.w}, {av1.x, av1.y, av1.z, av1.w}};
            float bv[2][4] = {{bv0.x, bv0.y, bv0.z, bv0.w}, {bv1.x, bv1.y, bv1.z, bv1.w}};
#pragma unroll
            for (int ii = 0; ii < 2; ++ii)
#pragma unroll
                for (int r = 0; r < 4; ++r)
#pragma unroll
                    for (int jj = 0; jj < 2; ++jj)
#pragma unroll
                        for (int w = 0; w < 4; ++w)
                            acc[ii][jj][r][w] += av[ii][r] * bv[jj][w];
        }
    }

    const int m0 = br * 128 + (ty << 2);
    const int n0 = bc * 128 + (tx << 2);
#pragma unroll
    for (int ii = 0; ii < 2; ++ii) {
#pragma unroll
        for (int r = 0; r < 4; ++r) {
            int m   = m0 + ii * 64 + r;
            int bb  = m >> 10;
            int tok = m & 1023;
#pragma unroll
            for (int jj = 0; jj < 2; ++jj) {
                int n     = n0 + jj * 64;
                int which = n / 768;            // 0=q 1=k 2=v
                int c     = n - which * 768;
                int head  = c >> 6;
                int d     = c & 63;
                size_t idx = (((size_t)(bb * 12 + head) << 10) + tok) * 64 + d;
                float v0 = acc[ii][jj][r][0] + bias[n + 0];
                float v1 = acc[ii][jj][r][1] + bias[n + 1];
                float v2 = acc[ii][jj][r][2] + bias[n + 2];
                float v3 = acc[ii][jj][r][3] + bias[n + 3];
                if (which == 0) {
                    float4 val = make_float4(v0 * 0.125f, v1 * 0.125f,
                                             v2 * 0.125f, v3 * 0.125f);
                    *(float4*)&qb[idx] = val;
                } else {
                    unsigned short* dst = (which == 1) ? kb : vb;
                    uint2 pk;
                    pk.x = (unsigned)f2bf(v0) | ((unsigned)f2bf(v1) << 16);
                    pk.y = (unsigned)f2bf(v2) | ((unsigned)f2bf(v3) << 16);
                    *(uint2*)&dst[idx] = pk;
                }
            }
        }
    }
}

// Output projection: fp32, unchanged.
__global__ __launch_bounds__(256) void proj_gemm(
    const float* __restrict__ A, const float* __restrict__ W,
    const float* __restrict__ bias, float* __restrict__ Out)
{
    __shared__ float As[16][132];
    __shared__ float Bs[16][132];
    const int t  = threadIdx.x;
    const int tx = t & 15;
    const int ty = t >> 4;
    const int bc = blockIdx.x;
    const int br = blockIdx.y;

    const int lrow = t >> 2;
    const int lkq  = (t & 3) << 2;

    const float* Ap = A + (size_t)(br * 128 + lrow) * 768 + lkq;
    const float* Wp = W + (size_t)(bc * 128 + lrow) * 768 + lkq;

    float acc[2][2][4][4];
#pragma unroll
    for (int i = 0; i < 2; ++i)
#pragma unroll
        for (int j = 0; j < 2; ++j)
#pragma unroll
            for (int r = 0; r < 4; ++r)
#pragma unroll
                for (int w = 0; w < 4; ++w) acc[i][j][r][w] = 0.f;

    for (int k0 = 0; k0 < 768; k0 += 16) {
        float4 a0 = *(const float4*)(Ap + k0);
        float4 a1 = *(const float4*)(Ap + (size_t)64 * 768 + k0);
        float4 b0 = *(const float4*)(Wp + k0);
        float4 b1 = *(const float4*)(Wp + (size_t)64 * 768 + k0);
        __syncthreads();
        As[lkq + 0][lrow] = a0.x; As[lkq + 1][lrow] = a0.y;
        As[lkq + 2][lrow] = a0.z; As[lkq + 3][lrow] = a0.w;
        As[lkq + 0][lrow + 64] = a1.x; As[lkq + 1][lrow + 64] = a1.y;
        As[lkq + 2][lrow + 64] = a1.z; As[lkq + 3][lrow + 64] = a1.w;
        Bs[lkq + 0][lrow] = b0.x; Bs[lkq + 1][lrow] = b0.y;
        Bs[lkq + 2][lrow] = b0.z; Bs[lkq + 3][lrow] = b0.w;
        Bs[lkq + 0][lrow + 64] = b1.x; Bs[lkq + 1][lrow + 64] = b1.y;
        Bs[lkq + 2][lrow + 64] = b1.z; Bs[lkq + 3][lrow + 64] = b1.w;
        __syncthreads();
#pragma unroll
        for (int kk = 0; kk < 16; ++kk) {
            float4 av0 = *(const float4*)&As[kk][ty << 2];
            float4 av1 = *(const float4*)&As[kk][(ty << 2) + 64];
            float4 bv0 = *(const float4*)&Bs[kk][tx << 2];
            float4 bv1 = *(const float4*)&Bs[kk][(tx << 2) + 64];
            float av[2][4] = {{av0.x, av0.y, av0.z, av0.w}, {av1.x, av1.y, av1.z, av1.w}};
            float bv[2][4] = {{bv0.x, bv0.y, bv0.z, bv0.w}, {bv1.x, bv1.y, bv1.z, bv1.w}};
#pragma unroll
            for (int ii = 0; ii < 2; ++ii)
#pragma unroll
                for (int r = 0; r < 4; ++r)
#pragma unroll
                    for (int jj = 0; jj < 2; ++jj)
#pragma unroll
                        for (int w = 0; w < 4; ++w)
                            acc[ii][jj][r][w] += av[ii][r] * bv[jj][w];
        }
    }

    const int m0 = br * 128 + (ty << 2);
    const int n0 = bc * 128 + (tx << 2);
#pragma unroll
    for (int ii = 0; ii < 2; ++ii) {
#pragma unroll
        for (int r = 0; r < 4; ++r) {
            int m = m0 + ii * 64 + r;
#pragma unroll
            for (int jj = 0; jj < 2; ++jj) {
                int n = n0 + jj * 64;
                float4 val;
                val.x = acc[ii][jj][r][0] + bias[n + 0];
                val.y = acc[ii][jj][r][1] + bias[n + 1];
                val.z = acc[ii][jj][r][2] + bias[n + 2];
                val.w = acc[ii][jj][r][3] + bias[n + 3];
                *(float4*)&Out[(size_t)m * 768 + n] = val;
            }
        }
    }
}

// ---------------------------------------------------------------------------
// MFMA flash attention with decomposed rel-pos bias.
// Block = (bh, 32-query tile), 128 threads = 2 waves; wave w owns q rows
// [w*16, w*16+16). 64-key tiles; QK^T and PV via mfma_f32_16x16x32_bf16.
// C-layout: col=lane&15, row=quad*4+reg.  A: A[m=lane&15][k=quad*8+j].
// B: B[k=quad*8+j][n=lane&15].  P transits LDS (bf16) C->A layout.
// All LDS tile strides are 72 bf16 = 144 B (16B-aligned b128 reads,
// bank-balanced: read start banks 4*(col16+quad)%32 cover all 32 banks).
// ---------------------------------------------------------------------------
__global__ __launch_bounds__(128) void attn_mfma(
    const float* __restrict__ Q, const unsigned short* __restrict__ K,
    const unsigned short* __restrict__ V, const float* __restrict__ Rh,
    const float* __restrict__ Rw, float* __restrict__ Out)
{
    typedef short s8v __attribute__((ext_vector_type(8)));
    typedef float f4v __attribute__((ext_vector_type(4)));

    const int t  = threadIdx.x;
    const int qt = blockIdx.x;    // image row of this q tile, 0..31
    const int bh = blockIdx.y;    // 0..95
    const int b  = bh / 12;
    const int h  = bh - b * 12;
    const int q0 = qt << 5;

    __shared__ float Qs[32][68];
    __shared__ float qh_tab[32][33];
    __shared__ float qw_tab[32][33];
    __shared__ unsigned short Ks[64][72];
    __shared__ unsigned short Vt[64][72];   // transposed: Vt[d][key]
    __shared__ unsigned short Pl[2][16][72];

    const float*          Qp = Q + ((size_t)bh * 1024 + q0) * 64;
    const unsigned short* Kp = K + (size_t)bh * 65536;
    const unsigned short* Vp = V + (size_t)bh * 65536;

    // stage Q fp32 (source for bias tables + bf16 A-frags)
    for (int id = t; id < 512; id += 128) {
        int row = id >> 4, fo = (id & 15) << 2;
        *(float4*)&Qs[row][fo] = *(const float4*)(Qp + row * 64 + fo);
    }
    __syncthreads();

    // bias tables: qh_tab[q][kb] = Q[q]·Rh[qt-kb+31]; qw_tab[q][c] = Q[q]·Rw[q-c+31]
    for (int p = t; p < 1024; p += 128) {
        int qq = p >> 5, c = p & 31;
        const float* rh = Rh + (qt - c + 31) * 64;
        const float* rw = Rw + (qq - c + 31) * 64;
        float ah = 0.f, aw = 0.f;
        for (int c4 = 0; c4 < 64; c4 += 4) {
            float4 qv = *(const float4*)&Qs[qq][c4];
            float4 hv = *(const float4*)(rh + c4);
            float4 wv = *(const float4*)(rw + c4);
            ah += qv.x * hv.x + qv.y * hv.y + qv.z * hv.z + qv.w * hv.w;
            aw += qv.x * wv.x + qv.y * wv.y + qv.z * wv.z + qv.w * wv.w;
        }
        qh_tab[qq][c] = ah;
        qw_tab[qq][c] = aw;
    }
    __syncthreads();

    const int wv    = t >> 6;      // wave id 0/1
    const int lane  = t & 63;
    const int col16 = lane & 15;
    const int quad  = lane >> 4;

    // Q A-frags (2 k-chunks of 32), fp32 LDS -> bf16 regs, once
    s8v qa[2];
#pragma unroll
    for (int c = 0; c < 2; ++c) {
        const float* src = &Qs[wv * 16 + col16][c * 32 + quad * 8];
        s8v f;
#pragma unroll
        for (int j = 0; j < 8; ++j) f[j] = (short)f2bf(src[j]);
        qa[c] = f;
    }

    f4v o[4];
#pragma unroll
    for (int nt = 0; nt < 4; ++nt) { o[nt][0] = 0.f; o[nt][1] = 0.f; o[nt][2] = 0.f; o[nt][3] = 0.f; }
    float mrun[4] = {NEG_INF, NEG_INF, NEG_INF, NEG_INF};
    float lrun[4] = {0.f, 0.f, 0.f, 0.f};

    for (int kt = 0; kt < 16; ++kt) {
        const int k0 = kt << 6;
        __syncthreads();    // previous tile fully consumed before overwrite

        // stage K tile (bf16 copy, coalesced uint2)
        for (int id = t; id < 1024; id += 128) {
            int row = id >> 4, d0 = (id & 15) << 2;
            *(uint2*)&Ks[row][d0] = *(const uint2*)(Kp + (size_t)(k0 + row) * 64 + d0);
        }
        // stage V transposed: lane owns key=lane(64 distinct) -> writes are 2 lanes/bank
        {
            int key   = t & 63;
            int dbase = (t >> 6) << 5;
            const unsigned short* vrow = Vp + (size_t)(k0 + key) * 64;
#pragma unroll
            for (int dg = 0; dg < 8; ++dg) {
                int d0 = dbase + (dg << 2);
                uint2 pk = *(const uint2*)(vrow + d0);
                Vt[d0 + 0][key] = (unsigned short)(pk.x & 0xffff);
                Vt[d0 + 1][key] = (unsigned short)(pk.x >> 16);
                Vt[d0 + 2][key] = (unsigned short)(pk.y & 0xffff);
                Vt[d0 + 3][key] = (unsigned short)(pk.y >> 16);
            }
        }
        __syncthreads();

        // S = Q·K^T : 4 key-tiles of 16, 2 chained k-chunks each
        f4v s4[4];
#pragma unroll
        for (int nt = 0; nt < 4; ++nt) {
            f4v acc; acc[0] = 0.f; acc[1] = 0.f; acc[2] = 0.f; acc[3] = 0.f;
            s8v b0 = *(const s8v*)&Ks[nt * 16 + col16][quad * 8];
            s8v b1 = *(const s8v*)&Ks[nt * 16 + col16][32 + quad * 8];
            acc = __builtin_amdgcn_mfma_f32_16x16x32_bf16(qa[0], b0, acc, 0, 0, 0);
            acc = __builtin_amdgcn_mfma_f32_16x16x32_bf16(qa[1], b1, acc, 0, 0, 0);
            s4[nt] = acc;
        }

        // bias add (qh uniform per tile -> broadcast; qw 16 cols)
        float sv[4][4];
#pragma unroll
        for (int nt = 0; nt < 4; ++nt) {
            int key_lo = ((nt & 1) << 4) + col16;   // key & 31
            int kb     = (kt << 1) + (nt >> 1);     // key >> 5
#pragma unroll
            for (int i = 0; i < 4; ++i) {
                int qr = wv * 16 + quad * 4 + i;
                sv[nt][i] = s4[nt][i] + qh_tab[qr][kb] + qw_tab[qr][key_lo];
            }
        }

        // online softmax (rows owned within wave; reduce across 16-lane col group)
        float alpha[4];
#pragma unroll
        for (int i = 0; i < 4; ++i) {
            float mx = fmaxf(fmaxf(sv[0][i], sv[1][i]), fmaxf(sv[2][i], sv[3][i]));
#pragma unroll
            for (int m = 8; m >= 1; m >>= 1)
                mx = fmaxf(mx, __shfl_xor(mx, m, 16));
            float mn = fmaxf(mrun[i], mx);
            alpha[i] = __expf(mrun[i] - mn);
            mrun[i]  = mn;
        }
#pragma unroll
        for (int i = 0; i < 4; ++i) {
            float ps = 0.f;
#pragma unroll
            for (int nt = 0; nt < 4; ++nt) {
                float pe = __expf(sv[nt][i] - mrun[i]);
                ps += pe;
                Pl[wv][quad * 4 + i][nt * 16 + col16] = f2bf(pe);
            }
#pragma unroll
            for (int m = 8; m >= 1; m >>= 1)
                ps += __shfl_xor(ps, m, 16);
            lrun[i] = lrun[i] * alpha[i] + ps;
        }
#pragma unroll
        for (int nt = 0; nt < 4; ++nt)
#pragma unroll
            for (int i = 0; i < 4; ++i)
                o[nt][i] *= alpha[i];

        // make this wave's P writes visible to its own b128 reads
        asm volatile("s_waitcnt lgkmcnt(0)" ::: "memory");

        // PV: A-frags of P (C->A via LDS), B-frags from Vt
        s8v pa0 = *(const s8v*)&Pl[wv][col16][quad * 8];
        s8v pa1 = *(const s8v*)&Pl[wv][col16][32 + quad * 8];
#pragma unroll
        for (int nt = 0; nt < 4; ++nt) {
            s8v vb0 = *(const s8v*)&Vt[nt * 16 + col16][quad * 8];
            s8v vb1 = *(const s8v*)&Vt[nt * 16 + col16][32 + quad * 8];
            o[nt] = __builtin_amdgcn_mfma_f32_16x16x32_bf16(pa0, vb0, o[nt], 0, 0, 0);
            o[nt] = __builtin_amdgcn_mfma_f32_16x16x32_bf16(pa1, vb1, o[nt], 0, 0, 0);
        }
    }

    // epilogue: O/l, scatter to (B,N,C) layout for proj
#pragma unroll
    for (int i = 0; i < 4; ++i) {
        float inv = 1.f / lrun[i];
        int   qr  = q0 + wv * 16 + quad * 4 + i;
        float* dst = Out + ((size_t)b * 1024 + qr) * 768 + h * 64;
#pragma unroll
        for (int nt = 0; nt < 4; ++nt)
            dst[nt * 16 + col16] = o[nt][i] * inv;
    }
}

extern "C" void kernel_launch(void* const* d_in, const int* in_sizes, int n_in,
                              void* d_out, int out_size, void* d_ws, size_t ws_size,
                              hipStream_t stream) {
    const float* x      = (const float*)d_in[0];
    const float* qkv_w  = (const float*)d_in[1];
    const float* qkv_b  = (const float*)d_in[2];
    const float* proj_w = (const float*)d_in[3];
    const float* proj_b = (const float*)d_in[4];
    const float* rel_h  = (const float*)d_in[5];
    const float* rel_w  = (const float*)d_in[6];
    float* out = (float*)d_out;

    float*          qbuf = (float*)d_ws;                         // fp32 [96][1024][64]
    unsigned short* kbuf = (unsigned short*)(qbuf + 6291456);    // bf16 [96][1024][64]
    unsigned short* vbuf = kbuf + 6291456;                       // bf16 [96][1024][64]
    float*          abuf = (float*)(vbuf + 6291456);             // fp32 [8192][768]

    qkv_gemm<<<dim3(18, 64), 256, 0, stream>>>(x, qkv_w, qkv_b, qbuf, kbuf, vbuf);
    attn_mfma<<<dim3(32, 96), 128, 0, stream>>>(qbuf, kbuf, vbuf, rel_h, rel_w, abuf);
    proj_gemm<<<dim3(6, 64), 256, 0, stream>>>(abuf, proj_w, proj_b, out);
}

// Round 4
// 934.289 us; speedup vs baseline: 1.3995x; 1.1080x over previous
//
#include <hip/hip_runtime.h>
#include <cstddef>

__device__ __forceinline__ unsigned short f2bf(float f) {
    union { float f; unsigned u; } v; v.f = f;
    unsigned r = v.u + 0x7fff + ((v.u >> 16) & 1);
    return (unsigned short)(r >> 16);
}

// ---------------------------------------------------------------------------
// SGEMM 128x128x16 tile, 256 threads, 8x8 microtile arranged as 2x2 of 4x4
// ---------------------------------------------------------------------------

// QKV projection. q -> fp32 [96][1024][64] (pre-scaled 0.125); k,v -> bf16.
__global__ __launch_bounds__(256) void qkv_gemm(
    const float* __restrict__ A, const float* __restrict__ W,
    const float* __restrict__ bias,
    float* __restrict__ qb, unsigned short* __restrict__ kb,
    unsigned short* __restrict__ vb)
{
    __shared__ float As[16][132];
    __shared__ float Bs[16][132];
    const int t  = threadIdx.x;
    const int tx = t & 15;
    const int ty = t >> 4;
    const int bc = blockIdx.x;    // N = 2304 (18 blocks)
    const int br = blockIdx.y;    // M = 8192 (64 blocks)

    const int lrow = t >> 2;
    const int lkq  = (t & 3) << 2;

    const float* Ap = A + (size_t)(br * 128 + lrow) * 768 + lkq;
    const float* Wp = W + (size_t)(bc * 128 + lrow) * 768 + lkq;

    float acc[2][2][4][4];
#pragma unroll
    for (int i = 0; i < 2; ++i)
#pragma unroll
        for (int j = 0; j < 2; ++j)
#pragma unroll
            for (int r = 0; r < 4; ++r)
#pragma unroll
                for (int w = 0; w < 4; ++w) acc[i][j][r][w] = 0.f;

    for (int k0 = 0; k0 < 768; k0 += 16) {
        float4 a0 = *(const float4*)(Ap + k0);
        float4 a1 = *(const float4*)(Ap + (size_t)64 * 768 + k0);
        float4 b0 = *(const float4*)(Wp + k0);
        float4 b1 = *(const float4*)(Wp + (size_t)64 * 768 + k0);
        __syncthreads();
        As[lkq + 0][lrow] = a0.x; As[lkq + 1][lrow] = a0.y;
        As[lkq + 2][lrow] = a0.z; As[lkq + 3][lrow] = a0.w;
        As[lkq + 0][lrow + 64] = a1.x; As[lkq + 1][lrow + 64] = a1.y;
        As[lkq + 2][lrow + 64] = a1.z; As[lkq + 3][lrow + 64] = a1.w;
        Bs[lkq + 0][lrow] = b0.x; Bs[lkq + 1][lrow] = b0.y;
        Bs[lkq + 2][lrow] = b0.z; Bs[lkq + 3][lrow] = b0.w;
        Bs[lkq + 0][lrow + 64] = b1.x; Bs[lkq + 1][lrow + 64] = b1.y;
        Bs[lkq + 2][lrow + 64] = b1.z; Bs[lkq + 3][lrow + 64] = b1.w;
        __syncthreads();
#pragma unroll
        for (int kk = 0; kk < 16; ++kk) {
            float4 av0 = *(const float4*)&As[kk][ty << 2];
            float4 av1 = *(const float4*)&As[kk][(ty << 2) + 64];
            float4 bv0 = *(const float4*)&Bs[kk][tx << 2];
            float4 bv1 = *(const float4*)&Bs[kk][(tx << 2) + 64];
            float av[2][4] = {{av0.x, av0.y, av0.z, av0.w}, {av1.x, av1.y, av1.z, av1.w}};
            float bv[2][4] = {{bv0.x, bv0.y, bv0.z, bv0.w}, {bv1.x, bv1.y, bv1.z, bv1.w}};
#pragma unroll
            for (int ii = 0; ii < 2; ++ii)
#pragma unroll
                for (int r = 0; r < 4; ++r)
#pragma unroll
                    for (int jj = 0; jj < 2; ++jj)
#pragma unroll
                        for (int w = 0; w < 4; ++w)
                            acc[ii][jj][r][w] += av[ii][r] * bv[jj][w];
        }
    }

    const int m0 = br * 128 + (ty << 2);
    const int n0 = bc * 128 + (tx << 2);
#pragma unroll
    for (int ii = 0; ii < 2; ++ii) {
#pragma unroll
        for (int r = 0; r < 4; ++r) {
            int m   = m0 + ii * 64 + r;
            int bb  = m >> 10;
            int tok = m & 1023;
#pragma unroll
            for (int jj = 0; jj < 2; ++jj) {
                int n     = n0 + jj * 64;
                int which = n / 768;            // 0=q 1=k 2=v
                int c     = n - which * 768;
                int head  = c >> 6;
                int d     = c & 63;
                size_t idx = (((size_t)(bb * 12 + head) << 10) + tok) * 64 + d;
                float v0 = acc[ii][jj][r][0] + bias[n + 0];
                float v1 = acc[ii][jj][r][1] + bias[n + 1];
                float v2 = acc[ii][jj][r][2] + bias[n + 2];
                float v3 = acc[ii][jj][r][3] + bias[n + 3];
                if (which == 0) {
                    float4 val = make_float4(v0 * 0.125f, v1 * 0.125f,
                                             v2 * 0.125f, v3 * 0.125f);
                    *(float4*)&qb[idx] = val;
                } else {
                    unsigned short* dst = (which == 1) ? kb : vb;
                    uint2 pk;
                    pk.x = (unsigned)f2bf(v0) | ((unsigned)f2bf(v1) << 16);
                    pk.y = (unsigned)f2bf(v2) | ((unsigned)f2bf(v3) << 16);
                    *(uint2*)&dst[idx] = pk;
                }
            }
        }
    }
}

// Output projection: fp32.
__global__ __launch_bounds__(256) void proj_gemm(
    const float* __restrict__ A, const float* __restrict__ W,
    const float* __restrict__ bias, float* __restrict__ Out)
{
    __shared__ float As[16][132];
    __shared__ float Bs[16][132];
    const int t  = threadIdx.x;
    const int tx = t & 15;
    const int ty = t >> 4;
    const int bc = blockIdx.x;
    const int br = blockIdx.y;

    const int lrow = t >> 2;
    const int lkq  = (t & 3) << 2;

    const float* Ap = A + (size_t)(br * 128 + lrow) * 768 + lkq;
    const float* Wp = W + (size_t)(bc * 128 + lrow) * 768 + lkq;

    float acc[2][2][4][4];
#pragma unroll
    for (int i = 0; i < 2; ++i)
#pragma unroll
        for (int j = 0; j < 2; ++j)
#pragma unroll
            for (int r = 0; r < 4; ++r)
#pragma unroll
                for (int w = 0; w < 4; ++w) acc[i][j][r][w] = 0.f;

    for (int k0 = 0; k0 < 768; k0 += 16) {
        float4 a0 = *(const float4*)(Ap + k0);
        float4 a1 = *(const float4*)(Ap + (size_t)64 * 768 + k0);
        float4 b0 = *(const float4*)(Wp + k0);
        float4 b1 = *(const float4*)(Wp + (size_t)64 * 768 + k0);
        __syncthreads();
        As[lkq + 0][lrow] = a0.x; As[lkq + 1][lrow] = a0.y;
        As[lkq + 2][lrow] = a0.z; As[lkq + 3][lrow] = a0.w;
        As[lkq + 0][lrow + 64] = a1.x; As[lkq + 1][lrow + 64] = a1.y;
        As[lkq + 2][lrow + 64] = a1.z; As[lkq + 3][lrow + 64] = a1.w;
        Bs[lkq + 0][lrow] = b0.x; Bs[lkq + 1][lrow] = b0.y;
        Bs[lkq + 2][lrow] = b0.z; Bs[lkq + 3][lrow] = b0.w;
        Bs[lkq + 0][lrow + 64] = b1.x; Bs[lkq + 1][lrow + 64] = b1.y;
        Bs[lkq + 2][lrow + 64] = b1.z; Bs[lkq + 3][lrow + 64] = b1.w;
        __syncthreads();
#pragma unroll
        for (int kk = 0; kk < 16; ++kk) {
            float4 av0 = *(const float4*)&As[kk][ty << 2];
            float4 av1 = *(const float4*)&As[kk][(ty << 2) + 64];
            float4 bv0 = *(const float4*)&Bs[kk][tx << 2];
            float4 bv1 = *(const float4*)&Bs[kk][(tx << 2) + 64];
            float av[2][4] = {{av0.x, av0.y, av0.z, av0.w}, {av1.x, av1.y, av1.z, av1.w}};
            float bv[2][4] = {{bv0.x, bv0.y, bv0.z, bv0.w}, {bv1.x, bv1.y, bv1.z, bv1.w}};
#pragma unroll
            for (int ii = 0; ii < 2; ++ii)
#pragma unroll
                for (int r = 0; r < 4; ++r)
#pragma unroll
                    for (int jj = 0; jj < 2; ++jj)
#pragma unroll
                        for (int w = 0; w < 4; ++w)
                            acc[ii][jj][r][w] += av[ii][r] * bv[jj][w];
        }
    }

    const int m0 = br * 128 + (ty << 2);
    const int n0 = bc * 128 + (tx << 2);
#pragma unroll
    for (int ii = 0; ii < 2; ++ii) {
#pragma unroll
        for (int r = 0; r < 4; ++r) {
            int m = m0 + ii * 64 + r;
#pragma unroll
            for (int jj = 0; jj < 2; ++jj) {
                int n = n0 + jj * 64;
                float4 val;
                val.x = acc[ii][jj][r][0] + bias[n + 0];
                val.y = acc[ii][jj][r][1] + bias[n + 1];
                val.z = acc[ii][jj][r][2] + bias[n + 2];
                val.w = acc[ii][jj][r][3] + bias[n + 3];
                *(float4*)&Out[(size_t)m * 768 + n] = val;
            }
        }
    }
}

// ---------------------------------------------------------------------------
// V transpose: [96][1024][64] bf16 -> Vt [96][64][1024] bf16
// ---------------------------------------------------------------------------
__global__ __launch_bounds__(256) void v_transpose(
    const unsigned short* __restrict__ V, unsigned short* __restrict__ Vt)
{
    __shared__ unsigned short Ls[64][72];
    const int t  = threadIdx.x;
    const int tc = blockIdx.x;
    const int bh = blockIdx.y;
    const unsigned short* src = V + (size_t)bh * 65536 + tc * 64 * 64;

    {
        int tok = t >> 2, dg = (t & 3) << 4;
        *(uint4*)&Ls[tok][dg]     = *(const uint4*)(src + tok * 64 + dg);
        *(uint4*)&Ls[tok][dg + 8] = *(const uint4*)(src + tok * 64 + dg + 8);
    }
    __syncthreads();
    {
        int d = t & 63, tg = (t >> 6) << 4;
        unsigned short tmp[16];
#pragma unroll
        for (int i = 0; i < 16; ++i) tmp[i] = Ls[tg + i][d];
        unsigned short* dst = Vt + (size_t)bh * 65536 + (size_t)d * 1024 + tc * 64 + tg;
        *(uint4*)&dst[0] = *(uint4*)&tmp[0];
        *(uint4*)&dst[8] = *(uint4*)&tmp[8];
    }
}

// ---------------------------------------------------------------------------
// Barrier-free MFMA flash attention with decomposed rel-pos bias.
// Block = (bh, 64-query tile = 2 image rows), 256 threads = 4 waves; wave w
// owns q rows [w*16, w*16+16) and iterates ALL 16 key-tiles independently —
// zero __syncthreads in the K-loop.
// B-frags (K for QK^T, Vt for PV) are single 16B loads straight from global
// (L1/L2-served). Softmax uses a FIXED shift (scores provably in [-~2,2];
// softmax is shift-invariant) -> no running max, no rescale, no per-tile
// reductions. Row-sum accumulated per-lane, one shuffle reduce at the end.
// P transits wave-private LDS (C->A layout) guarded by lgkmcnt only.
// RACE FIX (R3): ALL reads of the shared bias tables (qwr) happen strictly
// after the barrier that orders them against other waves' table writes.
// ---------------------------------------------------------------------------
__global__ __launch_bounds__(256) void attn_mfma(
    const float* __restrict__ Q, const unsigned short* __restrict__ K,
    const unsigned short* __restrict__ Vt, const float* __restrict__ Rh,
    const float* __restrict__ Rw, float* __restrict__ Out)
{
    typedef short s8v __attribute__((ext_vector_type(8)));
    typedef float f4v __attribute__((ext_vector_type(4)));

    const int t   = threadIdx.x;
    const int qt2 = blockIdx.x;   // 0..15: image rows 2*qt2, 2*qt2+1
    const int bh  = blockIdx.y;   // 0..95
    const int b   = bh / 12;
    const int h   = bh - b * 12;
    const int q0  = qt2 << 6;

    // LDS: [0,17408) Qs (init) / Pl (loop, 9216) union; then qh_tab, qw_tab
    __shared__ __align__(16) char smem[17408 + 8448 + 8448];
    float (*Qs)[68]            = (float (*)[68])smem;                    // 64x68 f32
    unsigned short (*Pl)[72]   = (unsigned short (*)[72])smem;           // 64x72 bf16
    float (*qh_tab)[33]        = (float (*)[33])(smem + 17408);          // 64x33
    float (*qw_tab)[33]        = (float (*)[33])(smem + 17408 + 8448);   // 64x33

    const float*          Qp = Q  + ((size_t)bh * 1024 + q0) * 64;
    const unsigned short* Kp = K  + (size_t)bh * 65536;
    const unsigned short* Vp = Vt + (size_t)bh * 65536;

    // stage Q fp32
    for (int id = t; id < 1024; id += 256) {
        int row = id >> 4, fo = (id & 15) << 2;
        *(float4*)&Qs[row][fo] = *(const float4*)(Qp + row * 64 + fo);
    }
    __syncthreads();

    // bias tables: qh_tab[qq][c] = Q[qq]·Rh[i_img-c+31], qw_tab[qq][c] = Q[qq]·Rw[(qq&31)-c+31]
    for (int p = t; p < 2048; p += 256) {
        int qq = p >> 5, c = p & 31;
        int i_img = (qt2 << 1) + (qq >> 5);
        const float* rh = Rh + (i_img - c + 31) * 64;
        const float* rw = Rw + ((qq & 31) - c + 31) * 64;
        float ah = 0.f, aw = 0.f;
        for (int c4 = 0; c4 < 64; c4 += 4) {
            float4 qv = *(const float4*)&Qs[qq][c4];
            float4 hv = *(const float4*)(rh + c4);
            float4 wv = *(const float4*)(rw + c4);
            ah += qv.x * hv.x + qv.y * hv.y + qv.z * hv.z + qv.w * hv.w;
            aw += qv.x * wv.x + qv.y * wv.y + qv.z * wv.z + qv.w * wv.w;
        }
        qh_tab[qq][c] = ah;
        qw_tab[qq][c] = aw;
    }

    const int wv    = t >> 6;      // wave 0..3
    const int lane  = t & 63;
    const int col16 = lane & 15;
    const int quad  = lane >> 4;
    const int qrow0 = wv << 4;     // this wave's q-row base (local)

    // Q A-frags (bf16): own-wave Qs reads, must complete before Pl overwrite
    s8v qa0, qa1;
    {
        const float* src = &Qs[qrow0 + col16][quad * 8];
        s8v f0, f1;
#pragma unroll
        for (int j = 0; j < 8; ++j) { f0[j] = (short)f2bf(src[j]); f1[j] = (short)f2bf(src[j + 32]); }
        qa0 = f0; qa1 = f1;
    }
    __syncthreads();   // (1) all table writes visible  (2) all Qs reads done

    // per-row qw values (key&31 = {col16, col16+16}) — tile-independent.
    // Safe ONLY after the barrier above (written by threads of other waves).
    float qwr[4][2];
#pragma unroll
    for (int i = 0; i < 4; ++i) {
        qwr[i][0] = qw_tab[qrow0 + quad * 4 + i][col16];
        qwr[i][1] = qw_tab[qrow0 + quad * 4 + i][col16 + 16];
    }

    f4v o[4];
#pragma unroll
    for (int nt = 0; nt < 4; ++nt) { o[nt][0] = 0.f; o[nt][1] = 0.f; o[nt][2] = 0.f; o[nt][3] = 0.f; }
    float lp[4] = {0.f, 0.f, 0.f, 0.f};

    for (int kt = 0; kt < 16; ++kt) {
        const int k0 = kt << 6;

        // S = Q·K^T : B-frags straight from global K (16B each)
        f4v s4[4];
#pragma unroll
        for (int nt = 0; nt < 4; ++nt) {
            const unsigned short* kp = Kp + (size_t)(k0 + nt * 16 + col16) * 64 + quad * 8;
            s8v b0 = *(const s8v*)kp;
            s8v b1 = *(const s8v*)(kp + 32);
            f4v acc; acc[0] = 0.f; acc[1] = 0.f; acc[2] = 0.f; acc[3] = 0.f;
            acc = __builtin_amdgcn_mfma_f32_16x16x32_bf16(qa0, b0, acc, 0, 0, 0);
            acc = __builtin_amdgcn_mfma_f32_16x16x32_bf16(qa1, b1, acc, 0, 0, 0);
            s4[nt] = acc;
        }

        // qh bias for this tile (2 key-row blocks), broadcast LDS reads
        float qh0[4], qh1[4];
#pragma unroll
        for (int i = 0; i < 4; ++i) {
            qh0[i] = qh_tab[qrow0 + quad * 4 + i][(kt << 1) + 0];
            qh1[i] = qh_tab[qrow0 + quad * 4 + i][(kt << 1) + 1];
        }

        // P = exp(S + bias - 16), fixed shift; accumulate row-sum per lane
#pragma unroll
        for (int nt = 0; nt < 4; ++nt) {
#pragma unroll
            for (int i = 0; i < 4; ++i) {
                float s  = s4[nt][i] + ((nt < 2) ? qh0[i] : qh1[i]) + qwr[i][nt & 1];
                float pe = __expf(s - 16.0f);
                lp[i] += pe;
                Pl[qrow0 + quad * 4 + i][nt * 16 + col16] = f2bf(pe);
            }
        }
        // wave-local visibility of P writes for the b128 reads below
        asm volatile("s_waitcnt lgkmcnt(0)" ::: "memory");

        // O += P·V : A-frags of P from LDS, B-frags straight from global Vt
        s8v pa0 = *(const s8v*)&Pl[qrow0 + col16][quad * 8];
        s8v pa1 = *(const s8v*)&Pl[qrow0 + col16][32 + quad * 8];
#pragma unroll
        for (int nt = 0; nt < 4; ++nt) {
            const unsigned short* vp = Vp + (size_t)(nt * 16 + col16) * 1024 + k0 + quad * 8;
            s8v vb0 = *(const s8v*)vp;
            s8v vb1 = *(const s8v*)(vp + 32);
            o[nt] = __builtin_amdgcn_mfma_f32_16x16x32_bf16(pa0, vb0, o[nt], 0, 0, 0);
            o[nt] = __builtin_amdgcn_mfma_f32_16x16x32_bf16(pa1, vb1, o[nt], 0, 0, 0);
        }
    }

    // final row-sum across the 16 col lanes, then write O/l
#pragma unroll
    for (int i = 0; i < 4; ++i) {
#pragma unroll
        for (int m = 8; m >= 1; m >>= 1) lp[i] += __shfl_xor(lp[i], m, 16);
    }
#pragma unroll
    for (int i = 0; i < 4; ++i) {
        float inv = 1.f / lp[i];
        int   qr  = q0 + qrow0 + quad * 4 + i;
        float* dst = Out + ((size_t)b * 1024 + qr) * 768 + h * 64;
#pragma unroll
        for (int nt = 0; nt < 4; ++nt)
            dst[nt * 16 + col16] = o[nt][i] * inv;
    }
}

extern "C" void kernel_launch(void* const* d_in, const int* in_sizes, int n_in,
                              void* d_out, int out_size, void* d_ws, size_t ws_size,
                              hipStream_t stream) {
    const float* x      = (const float*)d_in[0];
    const float* qkv_w  = (const float*)d_in[1];
    const float* qkv_b  = (const float*)d_in[2];
    const float* proj_w = (const float*)d_in[3];
    const float* proj_b = (const float*)d_in[4];
    const float* rel_h  = (const float*)d_in[5];
    const float* rel_w  = (const float*)d_in[6];
    float* out = (float*)d_out;

    char* ws = (char*)d_ws;
    float*          qbuf  = (float*)(ws);                         // fp32 [96][1024][64]  25165824 B
    unsigned short* kbuf  = (unsigned short*)(ws + 25165824);     // bf16 [96][1024][64]  12582912 B
    unsigned short* vbuf  = (unsigned short*)(ws + 37748736);     // bf16 [96][1024][64]  12582912 B
    unsigned short* vtbuf = (unsigned short*)(ws + 50331648);     // bf16 [96][64][1024]  12582912 B
    float*          abuf  = (float*)(ws + 62914560);              // fp32 [8192][768]     25165824 B

    qkv_gemm<<<dim3(18, 64), 256, 0, stream>>>(x, qkv_w, qkv_b, qbuf, kbuf, vbuf);
    v_transpose<<<dim3(16, 96), 256, 0, stream>>>(vbuf, vtbuf);
    attn_mfma<<<dim3(16, 96), 256, 0, stream>>>(qbuf, kbuf, vtbuf, rel_h, rel_w, abuf);
    proj_gemm<<<dim3(6, 64), 256, 0, stream>>>(abuf, proj_w, proj_b, out);
}

// Round 5
// 518.781 us; speedup vs baseline: 2.5204x; 1.8009x over previous
//
#include <hip/hip_runtime.h>
#include <cstddef>

typedef short s8v __attribute__((ext_vector_type(8)));
typedef float f4v __attribute__((ext_vector_type(4)));

__device__ __forceinline__ unsigned short f2bf(float f) {
    union { float f; unsigned u; } v; v.f = f;
    unsigned r = v.u + 0x7fff + ((v.u >> 16) & 1);
    return (unsigned short)(r >> 16);
}

// async global->LDS, 16B per lane. LDS dest is wave-uniform base + lane*16.
__device__ __forceinline__ void gl_lds16(const void* g, void* l) {
    __builtin_amdgcn_global_load_lds(
        (const __attribute__((address_space(1))) void*)g,
        (__attribute__((address_space(3))) void*)l, 16, 0, 0);
}

// ---------------------------------------------------------------------------
// f32 -> bf16 conversion, 8 elems/thread
// ---------------------------------------------------------------------------
__global__ __launch_bounds__(256) void to_bf16(
    const float* __restrict__ s, unsigned short* __restrict__ d, int n8)
{
    int i = blockIdx.x * 256 + threadIdx.x;
    if (i < n8) {
        float4 f0 = ((const float4*)s)[i * 2];
        float4 f1 = ((const float4*)s)[i * 2 + 1];
        uint4 pk;
        pk.x = (unsigned)f2bf(f0.x) | ((unsigned)f2bf(f0.y) << 16);
        pk.y = (unsigned)f2bf(f0.z) | ((unsigned)f2bf(f0.w) << 16);
        pk.z = (unsigned)f2bf(f1.x) | ((unsigned)f2bf(f1.y) << 16);
        pk.w = (unsigned)f2bf(f1.z) | ((unsigned)f2bf(f1.w) << 16);
        ((uint4*)d)[i] = pk;
    }
}

// ---------------------------------------------------------------------------
// bf16 MFMA GEMM, m97 structure: 128x128 tile, BK=32, 256 thr = 4 waves,
// each wave one 64x64 quadrant as 4x4 of 16x16x32 frags.
// C[m][n] = sum_k A[m][k] * W[n][k]; A,W bf16 K-contiguous.
// LDS tiles [128][32] bf16 UNPADDED (global_load_lds lane-order constraint).
// ---------------------------------------------------------------------------

// QKV: A = x_bf16 (8192x768), W = qkv_w_bf16 (2304x768).
// N-block of 128 lies entirely in q, k, or v (768 = 6 blocks of 128).
__global__ __launch_bounds__(256) void qkv_gemm_mfma(
    const unsigned short* __restrict__ A, const unsigned short* __restrict__ W,
    const float* __restrict__ bias,
    float* __restrict__ qb, unsigned short* __restrict__ kb,
    unsigned short* __restrict__ vb)
{
    __shared__ __align__(16) unsigned short As[128 * 32];
    __shared__ __align__(16) unsigned short Bs[128 * 32];
    const int t     = threadIdx.x;
    const int bc    = blockIdx.x;   // N = 2304 -> 18
    const int br    = blockIdx.y;   // M = 8192 -> 64
    const int wv    = t >> 6;
    const int lane  = t & 63;
    const int col16 = lane & 15;
    const int quad  = lane >> 4;
    const int w4    = lane >> 2;        // row within 16-row group
    const int k8    = (lane & 3) << 3;  // k offset 0/8/16/24
    const int mw    = wv >> 1, nw = wv & 1;

    const unsigned short* Ag = A + (size_t)(br * 128 + (wv << 5) + w4) * 768 + k8;
    const unsigned short* Wg = W + (size_t)(bc * 128 + (wv << 5) + w4) * 768 + k8;
    unsigned short* Asw = &As[(wv << 5) * 32];
    unsigned short* Bsw = &Bs[(wv << 5) * 32];

    f4v acc[4][4];
#pragma unroll
    for (int mt = 0; mt < 4; ++mt)
#pragma unroll
        for (int nt = 0; nt < 4; ++nt) {
            acc[mt][nt][0] = 0.f; acc[mt][nt][1] = 0.f;
            acc[mt][nt][2] = 0.f; acc[mt][nt][3] = 0.f;
        }

    for (int k0 = 0; k0 < 768; k0 += 32) {
        __syncthreads();
        gl_lds16(Ag + k0,             Asw);
        gl_lds16(Ag + k0 + 16 * 768,  Asw + 16 * 32);
        gl_lds16(Wg + k0,             Bsw);
        gl_lds16(Wg + k0 + 16 * 768,  Bsw + 16 * 32);
        __syncthreads();

        s8v a[4], b[4];
#pragma unroll
        for (int mt = 0; mt < 4; ++mt)
            a[mt] = *(const s8v*)&As[(mw * 64 + mt * 16 + col16) * 32 + quad * 8];
#pragma unroll
        for (int nt = 0; nt < 4; ++nt)
            b[nt] = *(const s8v*)&Bs[(nw * 64 + nt * 16 + col16) * 32 + quad * 8];
#pragma unroll
        for (int mt = 0; mt < 4; ++mt)
#pragma unroll
            for (int nt = 0; nt < 4; ++nt)
                acc[mt][nt] = __builtin_amdgcn_mfma_f32_16x16x32_bf16(
                    a[mt], b[nt], acc[mt][nt], 0, 0, 0);
    }

    // epilogue: scatter into [96][1024][64]; q fp32*0.125, k/v bf16
    const int which = bc / 6;                 // block-uniform
    const int cb    = (bc % 6) * 128 + nw * 64;
    const int m0    = br * 128 + mw * 64 + quad * 4;
#pragma unroll
    for (int nt = 0; nt < 4; ++nt) {
        int c    = cb + nt * 16 + col16;
        int head = c >> 6, d = c & 63;
        float bv = bias[which * 768 + c];
#pragma unroll
        for (int mt = 0; mt < 4; ++mt) {
#pragma unroll
            for (int i = 0; i < 4; ++i) {
                int m   = m0 + mt * 16 + i;
                int bbk = m >> 10, tok = m & 1023;
                size_t idx = (((size_t)(bbk * 12 + head) << 10) + tok) * 64 + d;
                float val = acc[mt][nt][i] + bv;
                if (which == 0)      qb[idx] = val * 0.125f;
                else if (which == 1) kb[idx] = f2bf(val);
                else                 vb[idx] = f2bf(val);
            }
        }
    }
}

// Proj: A = attn_out_bf16 (8192x768), W = proj_w_bf16 (768x768), fp32 out.
__global__ __launch_bounds__(256) void proj_gemm_mfma(
    const unsigned short* __restrict__ A, const unsigned short* __restrict__ W,
    const float* __restrict__ bias, float* __restrict__ Out)
{
    __shared__ __align__(16) unsigned short As[128 * 32];
    __shared__ __align__(16) unsigned short Bs[128 * 32];
    const int t     = threadIdx.x;
    const int bc    = blockIdx.x;   // N = 768 -> 6
    const int br    = blockIdx.y;   // M = 8192 -> 64
    const int wv    = t >> 6;
    const int lane  = t & 63;
    const int col16 = lane & 15;
    const int quad  = lane >> 4;
    const int w4    = lane >> 2;
    const int k8    = (lane & 3) << 3;
    const int mw    = wv >> 1, nw = wv & 1;

    const unsigned short* Ag = A + (size_t)(br * 128 + (wv << 5) + w4) * 768 + k8;
    const unsigned short* Wg = W + (size_t)(bc * 128 + (wv << 5) + w4) * 768 + k8;
    unsigned short* Asw = &As[(wv << 5) * 32];
    unsigned short* Bsw = &Bs[(wv << 5) * 32];

    f4v acc[4][4];
#pragma unroll
    for (int mt = 0; mt < 4; ++mt)
#pragma unroll
        for (int nt = 0; nt < 4; ++nt) {
            acc[mt][nt][0] = 0.f; acc[mt][nt][1] = 0.f;
            acc[mt][nt][2] = 0.f; acc[mt][nt][3] = 0.f;
        }

    for (int k0 = 0; k0 < 768; k0 += 32) {
        __syncthreads();
        gl_lds16(Ag + k0,             Asw);
        gl_lds16(Ag + k0 + 16 * 768,  Asw + 16 * 32);
        gl_lds16(Wg + k0,             Bsw);
        gl_lds16(Wg + k0 + 16 * 768,  Bsw + 16 * 32);
        __syncthreads();

        s8v a[4], b[4];
#pragma unroll
        for (int mt = 0; mt < 4; ++mt)
            a[mt] = *(const s8v*)&As[(mw * 64 + mt * 16 + col16) * 32 + quad * 8];
#pragma unroll
        for (int nt = 0; nt < 4; ++nt)
            b[nt] = *(const s8v*)&Bs[(nw * 64 + nt * 16 + col16) * 32 + quad * 8];
#pragma unroll
        for (int mt = 0; mt < 4; ++mt)
#pragma unroll
            for (int nt = 0; nt < 4; ++nt)
                acc[mt][nt] = __builtin_amdgcn_mfma_f32_16x16x32_bf16(
                    a[mt], b[nt], acc[mt][nt], 0, 0, 0);
    }

    const int m0 = br * 128 + mw * 64 + quad * 4;
#pragma unroll
    for (int nt = 0; nt < 4; ++nt) {
        int c    = bc * 128 + nw * 64 + nt * 16 + col16;
        float bv = bias[c];
#pragma unroll
        for (int mt = 0; mt < 4; ++mt) {
#pragma unroll
            for (int i = 0; i < 4; ++i) {
                int m = m0 + mt * 16 + i;
                Out[(size_t)m * 768 + c] = acc[mt][nt][i] + bv;
            }
        }
    }
}

// ---------------------------------------------------------------------------
// V transpose: [96][1024][64] bf16 -> Vt [96][64][1024] bf16
// ---------------------------------------------------------------------------
__global__ __launch_bounds__(256) void v_transpose(
    const unsigned short* __restrict__ V, unsigned short* __restrict__ Vt)
{
    __shared__ unsigned short Ls[64][72];
    const int t  = threadIdx.x;
    const int tc = blockIdx.x;
    const int bh = blockIdx.y;
    const unsigned short* src = V + (size_t)bh * 65536 + tc * 64 * 64;

    {
        int tok = t >> 2, dg = (t & 3) << 4;
        *(uint4*)&Ls[tok][dg]     = *(const uint4*)(src + tok * 64 + dg);
        *(uint4*)&Ls[tok][dg + 8] = *(const uint4*)(src + tok * 64 + dg + 8);
    }
    __syncthreads();
    {
        int d = t & 63, tg = (t >> 6) << 4;
        unsigned short tmp[16];
#pragma unroll
        for (int i = 0; i < 16; ++i) tmp[i] = Ls[tg + i][d];
        unsigned short* dst = Vt + (size_t)bh * 65536 + (size_t)d * 1024 + tc * 64 + tg;
        *(uint4*)&dst[0] = *(uint4*)&tmp[0];
        *(uint4*)&dst[8] = *(uint4*)&tmp[8];
    }
}

// ---------------------------------------------------------------------------
// Barrier-free MFMA flash attention with decomposed rel-pos bias (R4 kernel,
// unchanged except: output stored bf16 for the MFMA proj).
// ---------------------------------------------------------------------------
__global__ __launch_bounds__(256) void attn_mfma(
    const float* __restrict__ Q, const unsigned short* __restrict__ K,
    const unsigned short* __restrict__ Vt, const float* __restrict__ Rh,
    const float* __restrict__ Rw, unsigned short* __restrict__ Out)
{
    const int t   = threadIdx.x;
    const int qt2 = blockIdx.x;   // 0..15: image rows 2*qt2, 2*qt2+1
    const int bh  = blockIdx.y;   // 0..95
    const int b   = bh / 12;
    const int h   = bh - b * 12;
    const int q0  = qt2 << 6;

    __shared__ __align__(16) char smem[17408 + 8448 + 8448];
    float (*Qs)[68]            = (float (*)[68])smem;                    // 64x68 f32
    unsigned short (*Pl)[72]   = (unsigned short (*)[72])smem;           // 64x72 bf16
    float (*qh_tab)[33]        = (float (*)[33])(smem + 17408);
    float (*qw_tab)[33]        = (float (*)[33])(smem + 17408 + 8448);

    const float*          Qp = Q  + ((size_t)bh * 1024 + q0) * 64;
    const unsigned short* Kp = K  + (size_t)bh * 65536;
    const unsigned short* Vp = Vt + (size_t)bh * 65536;

    for (int id = t; id < 1024; id += 256) {
        int row = id >> 4, fo = (id & 15) << 2;
        *(float4*)&Qs[row][fo] = *(const float4*)(Qp + row * 64 + fo);
    }
    __syncthreads();

    for (int p = t; p < 2048; p += 256) {
        int qq = p >> 5, c = p & 31;
        int i_img = (qt2 << 1) + (qq >> 5);
        const float* rh = Rh + (i_img - c + 31) * 64;
        const float* rw = Rw + ((qq & 31) - c + 31) * 64;
        float ah = 0.f, aw = 0.f;
        for (int c4 = 0; c4 < 64; c4 += 4) {
            float4 qv = *(const float4*)&Qs[qq][c4];
            float4 hv = *(const float4*)(rh + c4);
            float4 wv = *(const float4*)(rw + c4);
            ah += qv.x * hv.x + qv.y * hv.y + qv.z * hv.z + qv.w * hv.w;
            aw += qv.x * wv.x + qv.y * wv.y + qv.z * wv.z + qv.w * wv.w;
        }
        qh_tab[qq][c] = ah;
        qw_tab[qq][c] = aw;
    }

    const int wv    = t >> 6;
    const int lane  = t & 63;
    const int col16 = lane & 15;
    const int quad  = lane >> 4;
    const int qrow0 = wv << 4;

    s8v qa0, qa1;
    {
        const float* src = &Qs[qrow0 + col16][quad * 8];
        s8v f0, f1;
#pragma unroll
        for (int j = 0; j < 8; ++j) { f0[j] = (short)f2bf(src[j]); f1[j] = (short)f2bf(src[j + 32]); }
        qa0 = f0; qa1 = f1;
    }
    __syncthreads();   // (1) all table writes visible  (2) all Qs reads done

    float qwr[4][2];
#pragma unroll
    for (int i = 0; i < 4; ++i) {
        qwr[i][0] = qw_tab[qrow0 + quad * 4 + i][col16];
        qwr[i][1] = qw_tab[qrow0 + quad * 4 + i][col16 + 16];
    }

    f4v o[4];
#pragma unroll
    for (int nt = 0; nt < 4; ++nt) { o[nt][0] = 0.f; o[nt][1] = 0.f; o[nt][2] = 0.f; o[nt][3] = 0.f; }
    float lp[4] = {0.f, 0.f, 0.f, 0.f};

    for (int kt = 0; kt < 16; ++kt) {
        const int k0 = kt << 6;

        f4v s4[4];
#pragma unroll
        for (int nt = 0; nt < 4; ++nt) {
            const unsigned short* kp = Kp + (size_t)(k0 + nt * 16 + col16) * 64 + quad * 8;
            s8v b0 = *(const s8v*)kp;
            s8v b1 = *(const s8v*)(kp + 32);
            f4v acc; acc[0] = 0.f; acc[1] = 0.f; acc[2] = 0.f; acc[3] = 0.f;
            acc = __builtin_amdgcn_mfma_f32_16x16x32_bf16(qa0, b0, acc, 0, 0, 0);
            acc = __builtin_amdgcn_mfma_f32_16x16x32_bf16(qa1, b1, acc, 0, 0, 0);
            s4[nt] = acc;
        }

        float qh0[4], qh1[4];
#pragma unroll
        for (int i = 0; i < 4; ++i) {
            qh0[i] = qh_tab[qrow0 + quad * 4 + i][(kt << 1) + 0];
            qh1[i] = qh_tab[qrow0 + quad * 4 + i][(kt << 1) + 1];
        }

#pragma unroll
        for (int nt = 0; nt < 4; ++nt) {
#pragma unroll
            for (int i = 0; i < 4; ++i) {
                float s  = s4[nt][i] + ((nt < 2) ? qh0[i] : qh1[i]) + qwr[i][nt & 1];
                float pe = __expf(s - 16.0f);
                lp[i] += pe;
                Pl[qrow0 + quad * 4 + i][nt * 16 + col16] = f2bf(pe);
            }
        }
        asm volatile("s_waitcnt lgkmcnt(0)" ::: "memory");

        s8v pa0 = *(const s8v*)&Pl[qrow0 + col16][quad * 8];
        s8v pa1 = *(const s8v*)&Pl[qrow0 + col16][32 + quad * 8];
#pragma unroll
        for (int nt = 0; nt < 4; ++nt) {
            const unsigned short* vp = Vp + (size_t)(nt * 16 + col16) * 1024 + k0 + quad * 8;
            s8v vb0 = *(const s8v*)vp;
            s8v vb1 = *(const s8v*)(vp + 32);
            o[nt] = __builtin_amdgcn_mfma_f32_16x16x32_bf16(pa0, vb0, o[nt], 0, 0, 0);
            o[nt] = __builtin_amdgcn_mfma_f32_16x16x32_bf16(pa1, vb1, o[nt], 0, 0, 0);
        }
    }

#pragma unroll
    for (int i = 0; i < 4; ++i) {
#pragma unroll
        for (int m = 8; m >= 1; m >>= 1) lp[i] += __shfl_xor(lp[i], m, 16);
    }
#pragma unroll
    for (int i = 0; i < 4; ++i) {
        float inv = 1.f / lp[i];
        int   qr  = q0 + qrow0 + quad * 4 + i;
        unsigned short* dst = Out + ((size_t)b * 1024 + qr) * 768 + h * 64;
#pragma unroll
        for (int nt = 0; nt < 4; ++nt)
            dst[nt * 16 + col16] = f2bf(o[nt][i] * inv);
    }
}

extern "C" void kernel_launch(void* const* d_in, const int* in_sizes, int n_in,
                              void* d_out, int out_size, void* d_ws, size_t ws_size,
                              hipStream_t stream) {
    const float* x      = (const float*)d_in[0];
    const float* qkv_w  = (const float*)d_in[1];
    const float* qkv_b  = (const float*)d_in[2];
    const float* proj_w = (const float*)d_in[3];
    const float* proj_b = (const float*)d_in[4];
    const float* rel_h  = (const float*)d_in[5];
    const float* rel_w  = (const float*)d_in[6];
    float* out = (float*)d_out;

    char* ws = (char*)d_ws;
    float*          qbuf  = (float*)(ws);                      // f32  [96][1024][64] 25165824
    unsigned short* kbuf  = (unsigned short*)(ws + 25165824);  // bf16 [96][1024][64] 12582912
    unsigned short* vbuf  = (unsigned short*)(ws + 37748736);  // bf16 [96][1024][64] 12582912
    unsigned short* vtbuf = (unsigned short*)(ws + 50331648);  // bf16 [96][64][1024] 12582912
    unsigned short* xab   = (unsigned short*)(ws + 62914560);  // bf16 x, later attn-out (8192x768) 12582912
    unsigned short* wqb   = (unsigned short*)(ws + 75497472);  // bf16 qkv_w (2304x768) 3538944
    unsigned short* wpb   = (unsigned short*)(ws + 79036416);  // bf16 proj_w (768x768) 1179648

    to_bf16<<<3072, 256, 0, stream>>>(x,      xab, 786432);
    to_bf16<<<864,  256, 0, stream>>>(qkv_w,  wqb, 221184);
    to_bf16<<<288,  256, 0, stream>>>(proj_w, wpb, 73728);

    qkv_gemm_mfma<<<dim3(18, 64), 256, 0, stream>>>(xab, wqb, qkv_b, qbuf, kbuf, vbuf);
    v_transpose<<<dim3(16, 96), 256, 0, stream>>>(vbuf, vtbuf);
    // NOTE: attn writes its bf16 output over xab (x_bf16 is dead after qkv_gemm)
    attn_mfma<<<dim3(16, 96), 256, 0, stream>>>(qbuf, kbuf, vtbuf, rel_h, rel_w, xab);
    proj_gemm_mfma<<<dim3(6, 64), 256, 0, stream>>>(xab, wpb, proj_b, out);
}

// Round 6
// 463.052 us; speedup vs baseline: 2.8238x; 1.1204x over previous
//
#include <hip/hip_runtime.h>
#include <cstddef>

typedef short s8v __attribute__((ext_vector_type(8)));
typedef float f4v __attribute__((ext_vector_type(4)));

__device__ __forceinline__ unsigned short f2bf(float f) {
    union { float f; unsigned u; } v; v.f = f;
    unsigned r = v.u + 0x7fff + ((v.u >> 16) & 1);
    return (unsigned short)(r >> 16);
}
__device__ __forceinline__ float bf2f(unsigned short u) {
    union { unsigned u; float f; } v; v.u = ((unsigned)u) << 16;
    return v.f;
}

// async global->LDS, 16B per lane. LDS dest is wave-uniform base + lane*16.
__device__ __forceinline__ void gl_lds16(const void* g, void* l) {
    __builtin_amdgcn_global_load_lds(
        (const __attribute__((address_space(1))) void*)g,
        (__attribute__((address_space(3))) void*)l, 16, 0, 0);
}

// ---------------------------------------------------------------------------
// f32 -> bf16 conversion, 8 elems/thread
// ---------------------------------------------------------------------------
__global__ __launch_bounds__(256) void to_bf16(
    const float* __restrict__ s, unsigned short* __restrict__ d, int n8)
{
    int i = blockIdx.x * 256 + threadIdx.x;
    if (i < n8) {
        float4 f0 = ((const float4*)s)[i * 2];
        float4 f1 = ((const float4*)s)[i * 2 + 1];
        uint4 pk;
        pk.x = (unsigned)f2bf(f0.x) | ((unsigned)f2bf(f0.y) << 16);
        pk.y = (unsigned)f2bf(f0.z) | ((unsigned)f2bf(f0.w) << 16);
        pk.z = (unsigned)f2bf(f1.x) | ((unsigned)f2bf(f1.y) << 16);
        pk.w = (unsigned)f2bf(f1.z) | ((unsigned)f2bf(f1.w) << 16);
        ((uint4*)d)[i] = pk;
    }
}

// ---------------------------------------------------------------------------
// bf16 MFMA GEMM, m97 structure: 128x128 tile, BK=32, 256 thr = 4 waves.
// ---------------------------------------------------------------------------
__global__ __launch_bounds__(256) void qkv_gemm_mfma(
    const unsigned short* __restrict__ A, const unsigned short* __restrict__ W,
    const float* __restrict__ bias,
    float* __restrict__ qb, unsigned short* __restrict__ kb,
    unsigned short* __restrict__ vb)
{
    __shared__ __align__(16) unsigned short As[128 * 32];
    __shared__ __align__(16) unsigned short Bs[128 * 32];
    const int t     = threadIdx.x;
    const int bc    = blockIdx.x;   // N = 2304 -> 18
    const int br    = blockIdx.y;   // M = 8192 -> 64
    const int wv    = t >> 6;
    const int lane  = t & 63;
    const int col16 = lane & 15;
    const int quad  = lane >> 4;
    const int w4    = lane >> 2;
    const int k8    = (lane & 3) << 3;
    const int mw    = wv >> 1, nw = wv & 1;

    const unsigned short* Ag = A + (size_t)(br * 128 + (wv << 5) + w4) * 768 + k8;
    const unsigned short* Wg = W + (size_t)(bc * 128 + (wv << 5) + w4) * 768 + k8;
    unsigned short* Asw = &As[(wv << 5) * 32];
    unsigned short* Bsw = &Bs[(wv << 5) * 32];

    f4v acc[4][4];
#pragma unroll
    for (int mt = 0; mt < 4; ++mt)
#pragma unroll
        for (int nt = 0; nt < 4; ++nt) {
            acc[mt][nt][0] = 0.f; acc[mt][nt][1] = 0.f;
            acc[mt][nt][2] = 0.f; acc[mt][nt][3] = 0.f;
        }

    for (int k0 = 0; k0 < 768; k0 += 32) {
        __syncthreads();
        gl_lds16(Ag + k0,             Asw);
        gl_lds16(Ag + k0 + 16 * 768,  Asw + 16 * 32);
        gl_lds16(Wg + k0,             Bsw);
        gl_lds16(Wg + k0 + 16 * 768,  Bsw + 16 * 32);
        __syncthreads();

        s8v a[4], b[4];
#pragma unroll
        for (int mt = 0; mt < 4; ++mt)
            a[mt] = *(const s8v*)&As[(mw * 64 + mt * 16 + col16) * 32 + quad * 8];
#pragma unroll
        for (int nt = 0; nt < 4; ++nt)
            b[nt] = *(const s8v*)&Bs[(nw * 64 + nt * 16 + col16) * 32 + quad * 8];
#pragma unroll
        for (int mt = 0; mt < 4; ++mt)
#pragma unroll
            for (int nt = 0; nt < 4; ++nt)
                acc[mt][nt] = __builtin_amdgcn_mfma_f32_16x16x32_bf16(
                    a[mt], b[nt], acc[mt][nt], 0, 0, 0);
    }

    const int which = bc / 6;
    const int cb    = (bc % 6) * 128 + nw * 64;
    const int m0    = br * 128 + mw * 64 + quad * 4;
#pragma unroll
    for (int nt = 0; nt < 4; ++nt) {
        int c    = cb + nt * 16 + col16;
        int head = c >> 6, d = c & 63;
        float bv = bias[which * 768 + c];
#pragma unroll
        for (int mt = 0; mt < 4; ++mt) {
#pragma unroll
            for (int i = 0; i < 4; ++i) {
                int m   = m0 + mt * 16 + i;
                int bbk = m >> 10, tok = m & 1023;
                size_t idx = (((size_t)(bbk * 12 + head) << 10) + tok) * 64 + d;
                float val = acc[mt][nt][i] + bv;
                if (which == 0)      qb[idx] = val * 0.125f;
                else if (which == 1) kb[idx] = f2bf(val);
                else                 vb[idx] = f2bf(val);
            }
        }
    }
}

__global__ __launch_bounds__(256) void proj_gemm_mfma(
    const unsigned short* __restrict__ A, const unsigned short* __restrict__ W,
    const float* __restrict__ bias, float* __restrict__ Out)
{
    __shared__ __align__(16) unsigned short As[128 * 32];
    __shared__ __align__(16) unsigned short Bs[128 * 32];
    const int t     = threadIdx.x;
    const int bc    = blockIdx.x;
    const int br    = blockIdx.y;
    const int wv    = t >> 6;
    const int lane  = t & 63;
    const int col16 = lane & 15;
    const int quad  = lane >> 4;
    const int w4    = lane >> 2;
    const int k8    = (lane & 3) << 3;
    const int mw    = wv >> 1, nw = wv & 1;

    const unsigned short* Ag = A + (size_t)(br * 128 + (wv << 5) + w4) * 768 + k8;
    const unsigned short* Wg = W + (size_t)(bc * 128 + (wv << 5) + w4) * 768 + k8;
    unsigned short* Asw = &As[(wv << 5) * 32];
    unsigned short* Bsw = &Bs[(wv << 5) * 32];

    f4v acc[4][4];
#pragma unroll
    for (int mt = 0; mt < 4; ++mt)
#pragma unroll
        for (int nt = 0; nt < 4; ++nt) {
            acc[mt][nt][0] = 0.f; acc[mt][nt][1] = 0.f;
            acc[mt][nt][2] = 0.f; acc[mt][nt][3] = 0.f;
        }

    for (int k0 = 0; k0 < 768; k0 += 32) {
        __syncthreads();
        gl_lds16(Ag + k0,             Asw);
        gl_lds16(Ag + k0 + 16 * 768,  Asw + 16 * 32);
        gl_lds16(Wg + k0,             Bsw);
        gl_lds16(Wg + k0 + 16 * 768,  Bsw + 16 * 32);
        __syncthreads();

        s8v a[4], b[4];
#pragma unroll
        for (int mt = 0; mt < 4; ++mt)
            a[mt] = *(const s8v*)&As[(mw * 64 + mt * 16 + col16) * 32 + quad * 8];
#pragma unroll
        for (int nt = 0; nt < 4; ++nt)
            b[nt] = *(const s8v*)&Bs[(nw * 64 + nt * 16 + col16) * 32 + quad * 8];
#pragma unroll
        for (int mt = 0; mt < 4; ++mt)
#pragma unroll
            for (int nt = 0; nt < 4; ++nt)
                acc[mt][nt] = __builtin_amdgcn_mfma_f32_16x16x32_bf16(
                    a[mt], b[nt], acc[mt][nt], 0, 0, 0);
    }

    const int m0 = br * 128 + mw * 64 + quad * 4;
#pragma unroll
    for (int nt = 0; nt < 4; ++nt) {
        int c    = bc * 128 + nw * 64 + nt * 16 + col16;
        float bv = bias[c];
#pragma unroll
        for (int mt = 0; mt < 4; ++mt) {
#pragma unroll
            for (int i = 0; i < 4; ++i) {
                int m = m0 + mt * 16 + i;
                Out[(size_t)m * 768 + c] = acc[mt][nt][i] + bv;
            }
        }
    }
}

// ---------------------------------------------------------------------------
// V transpose: [96][1024][64] bf16 -> Vt [96][64][1024] bf16
// ---------------------------------------------------------------------------
__global__ __launch_bounds__(256) void v_transpose(
    const unsigned short* __restrict__ V, unsigned short* __restrict__ Vt)
{
    __shared__ unsigned short Ls[64][72];
    const int t  = threadIdx.x;
    const int tc = blockIdx.x;
    const int bh = blockIdx.y;
    const unsigned short* src = V + (size_t)bh * 65536 + tc * 64 * 64;

    {
        int tok = t >> 2, dg = (t & 3) << 4;
        *(uint4*)&Ls[tok][dg]     = *(const uint4*)(src + tok * 64 + dg);
        *(uint4*)&Ls[tok][dg + 8] = *(const uint4*)(src + tok * 64 + dg + 8);
    }
    __syncthreads();
    {
        int d = t & 63, tg = (t >> 6) << 4;
        unsigned short tmp[16];
#pragma unroll
        for (int i = 0; i < 16; ++i) tmp[i] = Ls[tg + i][d];
        unsigned short* dst = Vt + (size_t)bh * 65536 + (size_t)d * 1024 + tc * 64 + tg;
        *(uint4*)&dst[0] = *(uint4*)&tmp[0];
        *(uint4*)&dst[8] = *(uint4*)&tmp[8];
    }
}

// ---------------------------------------------------------------------------
// Bias-table precompute: for every (bh, token, c in [0,32)):
//   qh[bh][tok][c] = Q[bh][tok] · Rh[(tok>>5) - c + 31]   (bf16 out)
//   qw[bh][tok][c] = Q[bh][tok] · Rw[(tok&31) - c + 31]   (bf16 out)
// grid (32 image rows, 96 bh), 256 threads.
// ---------------------------------------------------------------------------
__global__ __launch_bounds__(256) void bias_prep(
    const float* __restrict__ Q, const float* __restrict__ Rh,
    const float* __restrict__ Rw, unsigned short* __restrict__ qhb,
    unsigned short* __restrict__ qwb)
{
    __shared__ float Qs[32][68];
    const int t    = threadIdx.x;
    const int tc   = blockIdx.x;   // image row = token chunk of 32
    const int bh   = blockIdx.y;
    const int tok0 = tc << 5;
    const float* Qp = Q + ((size_t)bh * 1024 + tok0) * 64;

    for (int id = t; id < 512; id += 256) {
        int row = id >> 4, fo = (id & 15) << 2;
        *(float4*)&Qs[row][fo] = *(const float4*)(Qp + row * 64 + fo);
    }
    __syncthreads();

    for (int p = t; p < 1024; p += 256) {
        int j = p >> 5, c = p & 31;
        const float* rh = Rh + (tc - c + 31) * 64;
        const float* rw = Rw + (j - c + 31) * 64;
        float ah = 0.f, aw = 0.f;
        for (int d = 0; d < 64; d += 4) {
            float4 qv = *(const float4*)&Qs[j][d];
            float4 hv = *(const float4*)(rh + d);
            float4 wv = *(const float4*)(rw + d);
            ah += qv.x * hv.x + qv.y * hv.y + qv.z * hv.z + qv.w * hv.w;
            aw += qv.x * wv.x + qv.y * wv.y + qv.z * wv.z + qv.w * wv.w;
        }
        size_t o = (((size_t)bh << 10) + tok0 + j) * 32 + c;
        qhb[o] = f2bf(ah);
        qwb[o] = f2bf(aw);
    }
}

// ---------------------------------------------------------------------------
// Barrier-free MFMA flash attention, occupancy-optimized (R5):
//  - bias tables precomputed (bias_prep), copied bf16->f32 into LDS
//  - Q A-frags loaded directly from global (no Qs staging)
//  - LDS = 25.6 KB (qh 8K + qw 8K + Pl 9.2K) -> 6 blocks/CU
//  - __launch_bounds__(256,6) caps VGPR at 85 for 24 waves/CU
// K-loop identical to the proven R4 structure.
// ---------------------------------------------------------------------------
__global__ __launch_bounds__(256, 6) void attn_mfma(
    const float* __restrict__ Q, const unsigned short* __restrict__ K,
    const unsigned short* __restrict__ Vt,
    const unsigned short* __restrict__ qhb, const unsigned short* __restrict__ qwb,
    unsigned short* __restrict__ Out)
{
    const int t   = threadIdx.x;
    const int qt2 = blockIdx.x;   // 0..15: image rows 2*qt2, 2*qt2+1
    const int bh  = blockIdx.y;   // 0..95
    const int b   = bh / 12;
    const int h   = bh - b * 12;
    const int q0  = qt2 << 6;

    __shared__ float qh_s[64][32];
    __shared__ float qw_s[64][32];
    __shared__ unsigned short Pl[64][72];

    const unsigned short* Kp = K  + (size_t)bh * 65536;
    const unsigned short* Vp = Vt + (size_t)bh * 65536;

    // copy bias tables (bf16 global -> f32 LDS), 2048 entries each
    {
        const unsigned* qhp = (const unsigned*)(qhb + ((size_t)bh * 1024 + q0) * 32);
        const unsigned* qwp = (const unsigned*)(qwb + ((size_t)bh * 1024 + q0) * 32);
        for (int id = t; id < 1024; id += 256) {
            int row = id >> 4, c2 = (id & 15) << 1;
            unsigned ph = qhp[id];
            qh_s[row][c2]     = bf2f((unsigned short)(ph & 0xffff));
            qh_s[row][c2 + 1] = bf2f((unsigned short)(ph >> 16));
            unsigned pw = qwp[id];
            qw_s[row][c2]     = bf2f((unsigned short)(pw & 0xffff));
            qw_s[row][c2 + 1] = bf2f((unsigned short)(pw >> 16));
        }
    }

    const int wv    = t >> 6;
    const int lane  = t & 63;
    const int col16 = lane & 15;
    const int quad  = lane >> 4;
    const int qrow0 = wv << 4;

    // Q A-frags straight from global (fp32, pre-scaled 0.125)
    s8v qa0, qa1;
    {
        const float* qsrc = Q + ((size_t)bh * 1024 + q0 + qrow0 + col16) * 64 + quad * 8;
        float4 v0 = *(const float4*)qsrc;
        float4 v1 = *(const float4*)(qsrc + 4);
        float4 v2 = *(const float4*)(qsrc + 32);
        float4 v3 = *(const float4*)(qsrc + 36);
        s8v f0, f1;
        f0[0] = (short)f2bf(v0.x); f0[1] = (short)f2bf(v0.y);
        f0[2] = (short)f2bf(v0.z); f0[3] = (short)f2bf(v0.w);
        f0[4] = (short)f2bf(v1.x); f0[5] = (short)f2bf(v1.y);
        f0[6] = (short)f2bf(v1.z); f0[7] = (short)f2bf(v1.w);
        f1[0] = (short)f2bf(v2.x); f1[1] = (short)f2bf(v2.y);
        f1[2] = (short)f2bf(v2.z); f1[3] = (short)f2bf(v2.w);
        f1[4] = (short)f2bf(v3.x); f1[5] = (short)f2bf(v3.y);
        f1[6] = (short)f2bf(v3.z); f1[7] = (short)f2bf(v3.w);
        qa0 = f0; qa1 = f1;
    }
    __syncthreads();   // table copy complete (rows written by other waves)

    // per-row qw values (key&31 = {col16, col16+16}) — tile-independent
    float qwr[4][2];
#pragma unroll
    for (int i = 0; i < 4; ++i) {
        qwr[i][0] = qw_s[qrow0 + quad * 4 + i][col16];
        qwr[i][1] = qw_s[qrow0 + quad * 4 + i][col16 + 16];
    }

    f4v o[4];
#pragma unroll
    for (int nt = 0; nt < 4; ++nt) { o[nt][0] = 0.f; o[nt][1] = 0.f; o[nt][2] = 0.f; o[nt][3] = 0.f; }
    float lp[4] = {0.f, 0.f, 0.f, 0.f};

    for (int kt = 0; kt < 16; ++kt) {
        const int k0 = kt << 6;

        // S = Q·K^T : B-frags straight from global K (16B each)
        f4v s4[4];
#pragma unroll
        for (int nt = 0; nt < 4; ++nt) {
            const unsigned short* kp = Kp + (size_t)(k0 + nt * 16 + col16) * 64 + quad * 8;
            s8v b0 = *(const s8v*)kp;
            s8v b1 = *(const s8v*)(kp + 32);
            f4v acc; acc[0] = 0.f; acc[1] = 0.f; acc[2] = 0.f; acc[3] = 0.f;
            acc = __builtin_amdgcn_mfma_f32_16x16x32_bf16(qa0, b0, acc, 0, 0, 0);
            acc = __builtin_amdgcn_mfma_f32_16x16x32_bf16(qa1, b1, acc, 0, 0, 0);
            s4[nt] = acc;
        }

        // qh bias for this tile (2 key-row blocks), broadcast LDS reads
        float qh0[4], qh1[4];
#pragma unroll
        for (int i = 0; i < 4; ++i) {
            qh0[i] = qh_s[qrow0 + quad * 4 + i][(kt << 1) + 0];
            qh1[i] = qh_s[qrow0 + quad * 4 + i][(kt << 1) + 1];
        }

        // P = exp(S + bias - 16), fixed shift; accumulate row-sum per lane
#pragma unroll
        for (int nt = 0; nt < 4; ++nt) {
#pragma unroll
            for (int i = 0; i < 4; ++i) {
                float s  = s4[nt][i] + ((nt < 2) ? qh0[i] : qh1[i]) + qwr[i][nt & 1];
                float pe = __expf(s - 16.0f);
                lp[i] += pe;
                Pl[qrow0 + quad * 4 + i][nt * 16 + col16] = f2bf(pe);
            }
        }
        asm volatile("s_waitcnt lgkmcnt(0)" ::: "memory");

        // O += P·V : A-frags of P from LDS, B-frags straight from global Vt
        s8v pa0 = *(const s8v*)&Pl[qrow0 + col16][quad * 8];
        s8v pa1 = *(const s8v*)&Pl[qrow0 + col16][32 + quad * 8];
#pragma unroll
        for (int nt = 0; nt < 4; ++nt) {
            const unsigned short* vp = Vp + (size_t)(nt * 16 + col16) * 1024 + k0 + quad * 8;
            s8v vb0 = *(const s8v*)vp;
            s8v vb1 = *(const s8v*)(vp + 32);
            o[nt] = __builtin_amdgcn_mfma_f32_16x16x32_bf16(pa0, vb0, o[nt], 0, 0, 0);
            o[nt] = __builtin_amdgcn_mfma_f32_16x16x32_bf16(pa1, vb1, o[nt], 0, 0, 0);
        }
    }

#pragma unroll
    for (int i = 0; i < 4; ++i) {
#pragma unroll
        for (int m = 8; m >= 1; m >>= 1) lp[i] += __shfl_xor(lp[i], m, 16);
    }
#pragma unroll
    for (int i = 0; i < 4; ++i) {
        float inv = 1.f / lp[i];
        int   qr  = q0 + qrow0 + quad * 4 + i;
        unsigned short* dst = Out + ((size_t)b * 1024 + qr) * 768 + h * 64;
#pragma unroll
        for (int nt = 0; nt < 4; ++nt)
            dst[nt * 16 + col16] = f2bf(o[nt][i] * inv);
    }
}

extern "C" void kernel_launch(void* const* d_in, const int* in_sizes, int n_in,
                              void* d_out, int out_size, void* d_ws, size_t ws_size,
                              hipStream_t stream) {
    const float* x      = (const float*)d_in[0];
    const float* qkv_w  = (const float*)d_in[1];
    const float* qkv_b  = (const float*)d_in[2];
    const float* proj_w = (const float*)d_in[3];
    const float* proj_b = (const float*)d_in[4];
    const float* rel_h  = (const float*)d_in[5];
    const float* rel_w  = (const float*)d_in[6];
    float* out = (float*)d_out;

    char* ws = (char*)d_ws;
    float*          qbuf  = (float*)(ws);                      // f32  [96][1024][64] 25165824
    unsigned short* kbuf  = (unsigned short*)(ws + 25165824);  // bf16 [96][1024][64] 12582912
    unsigned short* vbuf  = (unsigned short*)(ws + 37748736);  // bf16 [96][1024][64] 12582912
    unsigned short* vtbuf = (unsigned short*)(ws + 50331648);  // bf16 [96][64][1024] 12582912
    unsigned short* xab   = (unsigned short*)(ws + 62914560);  // bf16 x / attn-out   12582912
    unsigned short* wqb   = (unsigned short*)(ws + 75497472);  // bf16 qkv_w          3538944
    unsigned short* wpb   = (unsigned short*)(ws + 79036416);  // bf16 proj_w         1179648
    // bias tables overlay the dead vbuf region after v_transpose:
    unsigned short* qhb   = vbuf;                              // bf16 [96][1024][32] 6291456
    unsigned short* qwb   = vbuf + 3145728;                    // bf16 [96][1024][32] 6291456

    to_bf16<<<3072, 256, 0, stream>>>(x,      xab, 786432);
    to_bf16<<<864,  256, 0, stream>>>(qkv_w,  wqb, 221184);
    to_bf16<<<288,  256, 0, stream>>>(proj_w, wpb, 73728);

    qkv_gemm_mfma<<<dim3(18, 64), 256, 0, stream>>>(xab, wqb, qkv_b, qbuf, kbuf, vbuf);
    v_transpose<<<dim3(16, 96), 256, 0, stream>>>(vbuf, vtbuf);
    bias_prep<<<dim3(32, 96), 256, 0, stream>>>(qbuf, rel_h, rel_w, qhb, qwb);
    attn_mfma<<<dim3(16, 96), 256, 0, stream>>>(qbuf, kbuf, vtbuf, qhb, qwb, xab);
    proj_gemm_mfma<<<dim3(6, 64), 256, 0, stream>>>(xab, wpb, proj_b, out);
}